// Round 7
// baseline (2179.105 us; speedup 1.0000x reference)
//
#include <hip/hip_runtime.h>
#include <hip/hip_bf16.h>
#include <stdint.h>

// ---- problem constants ----
#define NB   65536      // batch points
#define NC   2
#define NV   3
#define ND   64
#define NK   1024       // codebook entries
#define NS   4
#define NH   1024
#define NL   5
#define NF   25
#define NIN  102
#define K0P  128        // padded layer-0 K

typedef __bf16 bf16x8 __attribute__((ext_vector_type(8)));
typedef __bf16 bf16x4 __attribute__((ext_vector_type(4)));
typedef float  f32x4  __attribute__((ext_vector_type(4)));

// ---------------------------------------------------------------------------
// VQ kernel: single block, 1024 threads (one codebook row per thread).
// ---------------------------------------------------------------------------
__global__ __launch_bounds__(1024) void vq_kernel(
    const float* __restrict__ latents, const int* __restrict__ latent_idx,
    const float* __restrict__ codebooks, float* __restrict__ zq_out,
    float* __restrict__ out) {
    __shared__ float zcur[ND], resid[ND], zqsum[ND], ssq[ND];
    __shared__ float sDw[16];
    __shared__ int   sKw[16];
    __shared__ int   sBest;
    int t = threadIdx.x, lane = t & 63, wv = t >> 6;
    const float* img = latents + (size_t)latent_idx[0] * (NS * ND);
    if (t < ND) { resid[t] = 0.f; zqsum[t] = 0.f; }
    __syncthreads();
    float lossAcc = 0.f;   // thread 0 only
    for (int s = 0; s < NS; s++) {
        if (t < ND) {
            float iv = img[s * ND + t];
            float r  = resid[t] + iv;
            resid[t] = r;
            zcur[t]  = (s == 0) ? iv : (r - zqsum[t]);
        }
        __syncthreads();
        float zz = 0.f;
#pragma unroll
        for (int d = 0; d < ND; d++) { float z = zcur[d]; zz += z * z; }
        const float4* e4 = (const float4*)(codebooks + ((size_t)s * NK + t) * ND);
        float dot = 0.f, ee = 0.f;
#pragma unroll
        for (int i = 0; i < 16; i++) {
            float4 v = e4[i];
            dot += zcur[4 * i + 0] * v.x; dot += zcur[4 * i + 1] * v.y;
            dot += zcur[4 * i + 2] * v.z; dot += zcur[4 * i + 3] * v.w;
            ee  += v.x * v.x; ee += v.y * v.y; ee += v.z * v.z; ee += v.w * v.w;
        }
        float dmin = zz - 2.0f * dot + ee;
        int   kmin = t;
#pragma unroll
        for (int m = 1; m < 64; m <<= 1) {
            float d2 = __shfl_xor(dmin, m);
            int   k2 = __shfl_xor(kmin, m);
            if (d2 < dmin || (d2 == dmin && k2 < kmin)) { dmin = d2; kmin = k2; }
        }
        if (lane == 0) { sDw[wv] = dmin; sKw[wv] = kmin; }
        __syncthreads();
        if (t == 0) {
            float bd = sDw[0]; int bk = sKw[0];
            for (int w = 1; w < 16; w++) {
                float d2 = sDw[w]; int k2 = sKw[w];
                if (d2 < bd || (d2 == bd && k2 < bk)) { bd = d2; bk = k2; }
            }
            sBest = bk;
            out[NB * NV + s] = (float)bk;
        }
        __syncthreads();
        int best = sBest;
        const float* eb = codebooks + ((size_t)s * NK + best) * ND;
        if (t < ND) {
            float zq = eb[t];
            float d  = zq - zcur[t];
            ssq[t]   = d * d;
            zqsum[t] = zqsum[t] + (zq + (zcur[t] - zq));   // z_q_st forward (exact ref arith)
        }
        __syncthreads();
        if (t == 0) {
            float sum = 0.f;
            for (int d = 0; d < ND; d++) sum += ssq[d];
            lossAcc += 0.25f * (sum / (float)ND);
        }
    }
    if (t < ND) zq_out[t] = zqsum[t];
    if (t == 0) out[NB * NV + NS] = lossAcc;
}

// ---------------------------------------------------------------------------
// betas fused with decoder biases
// ---------------------------------------------------------------------------
__global__ __launch_bounds__(256) void betas_kernel(
    const float* __restrict__ zq, const float* __restrict__ mod_W,
    const float* __restrict__ mod_b, const float* __restrict__ b0,
    const float* __restrict__ bh, float* __restrict__ bb) {
    int g = blockIdx.x * 256 + threadIdx.x;   // < 5120
    int l = g >> 10, n = g & 1023;
    float acc = mod_b[g];
    for (int d = 0; d < ND; d++) acc += zq[d] * mod_W[(size_t)(l * ND + d) * NH + n];
    acc += (l == 0) ? b0[n] : bh[(size_t)(l - 1) * NH + n];
    bb[g] = acc;
}

// ---------------------------------------------------------------------------
// out init: values[m][v] = bout[v] (atomic-add target for the fused layer)
// ---------------------------------------------------------------------------
__global__ __launch_bounds__(256) void init_out_kernel(
    const float* __restrict__ bout, float* __restrict__ out) {
    int g = blockIdx.x * 256 + threadIdx.x;   // < NB*NV
    out[g] = bout[g % NV];
}

// ---------------------------------------------------------------------------
// Weight prep: fp32 [Ks][1024] -> bf16 transposed [1024][Kp] (zero-pad k>=Ks)
// ---------------------------------------------------------------------------
__global__ __launch_bounds__(256) void prep_kernel(
    const float* __restrict__ src, __bf16* __restrict__ dst, int Ks, int Kp) {
    __shared__ float tile[32][33];
    src += (size_t)blockIdx.z * Ks * NH;
    dst += (size_t)blockIdx.z * NH * Kp;
    int k0 = blockIdx.x * 32, n0 = blockIdx.y * 32;
    int tx = threadIdx.x, ty = threadIdx.y;   // (32, 8)
    for (int i = 0; i < 4; i++) {
        int k = k0 + ty + i * 8;
        int n = n0 + tx;
        tile[ty + i * 8][tx] = (k < Ks) ? src[(size_t)k * NH + n] : 0.0f;
    }
    __syncthreads();
    for (int i = 0; i < 4; i++) {
        int n = n0 + ty + i * 8;
        int k = k0 + tx;
        dst[(size_t)n * Kp + k] = (__bf16)tile[tx][ty + i * 8];
    }
}

// ---------------------------------------------------------------------------
// Positional encoding for a batch chunk -> bf16 [Bc][128], zero-pad 102..127
// ---------------------------------------------------------------------------
__global__ __launch_bounds__(256) void pe_kernel(
    const float* __restrict__ coords, __bf16* __restrict__ pe) {
    int g = blockIdx.x * 256 + threadIdx.x;   // < Bc*128
    int m = g >> 7, k = g & 127;
    float v = 0.0f;
    if (k < 2) {
        v = coords[m * 2 + k];
    } else if (k < NIN) {
        int u = k - 2;
        int f = u >> 2, r = u & 3;
        float c = coords[m * 2 + (r & 1)];
        float a = c * __builtin_ldexpf(3.14159274101257324f, f);
        v = (r < 2) ? sinf(a) : cosf(a);
    }
    pe[g] = (__bf16)v;
}

// ---------------------------------------------------------------------------
// MFMA GEMM, R7: DIRECT-GLOBAL FRAGMENTS — no LDS, no barriers.
// Both A[M][K] and W[N][K] are K-major, and the 16x16x32 bf16 MFMA operand
// layout is "row = lane&15, 8 consecutive k at quad*8" for BOTH operands, so
// each lane's fragment is one 16B global_load_dwordx4 (wave touches 16 full
// 64B lines -> coalesced). The R2-R6 LDS was a no-op layout transform whose
// barrier serialized every wave each K-step (flat 27% MfmaUtil, dbuf neutral).
// With no barriers the compiler software-pipelines loads across K freely.
// 128x128 block tile, 4 waves 2x2, wave tile 64x64, K compile-time.
// XCD-residue grid decode kept (verified R4: FETCH 265->53 MB).
// MODE 0: O = relu(acc+bb) stored bf16 packed 8B.
// MODE 1: out[m][v] += relu(acc+bb).Wout[n][v], q-lane shfl reduce + atomicAdd.
// ---------------------------------------------------------------------------
template <int MODE, int KT>
__global__ __launch_bounds__(256, 4) void gemm_kernel(
    const __bf16* __restrict__ A, const __bf16* __restrict__ W,
    const float* __restrict__ bb, __bf16* __restrict__ O,
    const float* __restrict__ Wout, float* __restrict__ out, int Mb) {
    int t   = threadIdx.x;
    int fid = blockIdx.x;
    int xcd = fid & 7;
    int j8  = fid >> 3;                 // 0..Mb-1
    int bn  = j8 & 7;                   // fastest within an XCD
    int bm  = xcd * (Mb >> 3) + (j8 >> 3);
    int lane = t & 63, wv = t >> 6;
    int wm   = wv >> 1, wn = wv & 1;
    int q    = lane >> 4, r16 = lane & 15;

    // loop-invariant fragment row pointers (already offset by quad's k=q*8)
    const __bf16* pA[4];
    const __bf16* pW[4];
#pragma unroll
    for (int i = 0; i < 4; i++) {
        pA[i] = A + (size_t)(bm * 128 + wm * 64 + i * 16 + r16) * KT + q * 8;
        pW[i] = W + (size_t)(bn * 128 + wn * 64 + i * 16 + r16) * KT + q * 8;
    }

    f32x4 acc[4][4];
    f32x4 zero = {0.f, 0.f, 0.f, 0.f};
    for (int i = 0; i < 4; i++)
        for (int j = 0; j < 4; j++) acc[i][j] = zero;

#pragma unroll 2
    for (int it = 0; it < (KT >> 5); it++) {
        int k0 = it << 5;
        bf16x8 af[4], bfr[4];
#pragma unroll
        for (int i = 0; i < 4; i++) {
            af[i]  = *(const bf16x8*)(pA[i] + k0);
            bfr[i] = *(const bf16x8*)(pW[i] + k0);
        }
        // swapped operands: acc[i][j] rows (q*4+r) = n-dim(j), cols (r16) = m-dim(i)
#pragma unroll
        for (int i = 0; i < 4; i++)
#pragma unroll
            for (int j = 0; j < 4; j++)
                acc[i][j] = __builtin_amdgcn_mfma_f32_16x16x32_bf16(bfr[j], af[i], acc[i][j], 0, 0, 0);
    }

    // lane element (i,j,r):  m = bm*128+wm*64+i*16+r16,  n = bn*128+wn*64+j*16+q*4+r
    if constexpr (MODE == 0) {
#pragma unroll
        for (int j = 0; j < 4; j++) {
            int nb = bn * 128 + wn * 64 + j * 16 + q * 4;
            f32x4 b4 = *(const f32x4*)(bb + nb);
#pragma unroll
            for (int i = 0; i < 4; i++) {
                int m = bm * 128 + wm * 64 + i * 16 + r16;
                bf16x4 o4;
#pragma unroll
                for (int r = 0; r < 4; r++)
                    o4[r] = (__bf16)fmaxf(acc[i][j][r] + b4[r], 0.0f);
                *(bf16x4*)(O + (size_t)m * NH + nb) = o4;
            }
        }
    } else {
#pragma unroll
        for (int i = 0; i < 4; i++) {
            float p0 = 0.f, p1 = 0.f, p2 = 0.f;
#pragma unroll
            for (int j = 0; j < 4; j++) {
                int nb = bn * 128 + wn * 64 + j * 16 + q * 4;
                f32x4 b4 = *(const f32x4*)(bb + nb);
#pragma unroll
                for (int r = 0; r < 4; r++) {
                    float val = fmaxf(acc[i][j][r] + b4[r], 0.0f);
                    const float* w = Wout + (size_t)(nb + r) * NV;
                    p0 += val * w[0]; p1 += val * w[1]; p2 += val * w[2];
                }
            }
            // reduce over the 4 q-lanes (lane bits 4,5) holding the same m
            p0 += __shfl_xor(p0, 16); p0 += __shfl_xor(p0, 32);
            p1 += __shfl_xor(p1, 16); p1 += __shfl_xor(p1, 32);
            p2 += __shfl_xor(p2, 16); p2 += __shfl_xor(p2, 32);
            if (q == 0) {
                int m = bm * 128 + wm * 64 + i * 16 + r16;
                atomicAdd(&out[(size_t)m * NV + 0], p0);
                atomicAdd(&out[(size_t)m * NV + 1], p1);
                atomicAdd(&out[(size_t)m * NV + 2], p2);
            }
        }
    }
}

// ---------------------------------------------------------------------------
extern "C" void kernel_launch(void* const* d_in, const int* in_sizes, int n_in,
                              void* d_out, int out_size, void* d_ws, size_t ws_size,
                              hipStream_t stream) {
    const float* coords     = (const float*)d_in[0];
    const int*   latent_idx = (const int*)d_in[1];
    const float* latents    = (const float*)d_in[2];
    const float* codebooks  = (const float*)d_in[3];
    const float* mod_W      = (const float*)d_in[4];
    const float* mod_b      = (const float*)d_in[5];
    const float* dec_W0     = (const float*)d_in[6];
    const float* dec_b0     = (const float*)d_in[7];
    const float* dec_Wh     = (const float*)d_in[8];
    const float* dec_bh     = (const float*)d_in[9];
    const float* dec_Wout   = (const float*)d_in[10];
    const float* dec_bout   = (const float*)d_in[11];
    float* out = (float*)d_out;

    // ---- workspace layout (fixed part ~8.67 MB) ----
    char* wsb = (char*)d_ws;
    float*  zq  = (float*)(wsb + 0);                       //      256 B
    float*  bb  = (float*)(wsb + 256);                     //   20,480 B
    __bf16* W0T = (__bf16*)(wsb + 20736);                  //  262,144 B  [1024][128]
    __bf16* WhT = (__bf16*)(wsb + 282880);                 // 8,388,608 B [4][1024][1024]
    const size_t fixed_end = 8671488;

    // adaptive chunk: cap 65536, halve until fits; floor 1024 so Mb%8==0.
    // Deterministic in ws_size -> identical launch sequence (capture-safe).
    int Bc = 65536;
    while (Bc > 1024 && fixed_end + 2 * (size_t)Bc * NH * sizeof(__bf16) > ws_size)
        Bc >>= 1;
    int Mb = Bc / 128;

    __bf16* hA = (__bf16*)(wsb + fixed_end);               // [Bc][1024]
    __bf16* hB = hA + (size_t)Bc * NH;                     // [Bc][1024]
    __bf16* pe = hB;   // pe [Bc][128] aliases hB (dead before layer-1 writes hB)

    // ---- one-time (per call) small kernels ----
    vq_kernel<<<1, 1024, 0, stream>>>(latents, latent_idx, codebooks, zq, out);
    betas_kernel<<<20, 256, 0, stream>>>(zq, mod_W, mod_b, dec_b0, dec_bh, bb);
    init_out_kernel<<<(NB * NV) / 256, 256, 0, stream>>>(dec_bout, out);
    prep_kernel<<<dim3(4, 32, 1), dim3(32, 8), 0, stream>>>(dec_W0, W0T, NIN, K0P);
    prep_kernel<<<dim3(32, 32, 4), dim3(32, 8), 0, stream>>>(dec_Wh, WhT, NH, NH);

    // ---- chunked 5-layer MLP, output layer fused into the last GEMM ----
    for (int c0 = 0; c0 < NB; c0 += Bc) {
        pe_kernel<<<(Bc * 128) / 256, 256, 0, stream>>>(coords + (size_t)c0 * NC, pe);
        gemm_kernel<0, K0P><<<8 * Mb, 256, 0, stream>>>(
            pe, W0T, bb + 0 * NH, hA, nullptr, nullptr, Mb);
        gemm_kernel<0, NH><<<8 * Mb, 256, 0, stream>>>(
            hA, WhT + 0 * (size_t)NH * NH, bb + 1 * NH, hB, nullptr, nullptr, Mb);
        gemm_kernel<0, NH><<<8 * Mb, 256, 0, stream>>>(
            hB, WhT + 1 * (size_t)NH * NH, bb + 2 * NH, hA, nullptr, nullptr, Mb);
        gemm_kernel<0, NH><<<8 * Mb, 256, 0, stream>>>(
            hA, WhT + 2 * (size_t)NH * NH, bb + 3 * NH, hB, nullptr, nullptr, Mb);
        gemm_kernel<1, NH><<<8 * Mb, 256, 0, stream>>>(
            hB, WhT + 3 * (size_t)NH * NH, bb + 4 * NH, nullptr,
            dec_Wout, out + (size_t)c0 * NV, Mb);
    }
}

// Round 8
// 700.312 us; speedup vs baseline: 3.1116x; 3.1116x over previous
//
#include <hip/hip_runtime.h>
#include <hip/hip_bf16.h>
#include <stdint.h>

// ---- problem constants ----
#define NB   65536      // batch points
#define NC   2
#define NV   3
#define ND   64
#define NK   1024       // codebook entries
#define NS   4
#define NH   1024
#define NL   5
#define NF   25
#define NIN  102
#define K0P  128        // padded layer-0 K

typedef float f32x4 __attribute__((ext_vector_type(4)));
typedef int   i32x4 __attribute__((ext_vector_type(4)));
typedef int   i32x8 __attribute__((ext_vector_type(8)));
typedef unsigned char u8;

__device__ __forceinline__ void load_lds16(const void* g, void* l) {
    __builtin_amdgcn_global_load_lds(
        (const __attribute__((address_space(1))) void*)g,
        (__attribute__((address_space(3))) void*)l,
        16, 0, 0);
}

// fp8 e4m3 scalar convert (RNE, saturating): low byte of cvt_pk
__device__ __forceinline__ u8 to_fp8(float x) {
    return (u8)(__builtin_amdgcn_cvt_pk_fp8_f32(x, 0.0f, 0, false) & 0xff);
}

// ---------------------------------------------------------------------------
// VQ kernel: single block, 1024 threads (one codebook row per thread). fp32.
// ---------------------------------------------------------------------------
__global__ __launch_bounds__(1024) void vq_kernel(
    const float* __restrict__ latents, const int* __restrict__ latent_idx,
    const float* __restrict__ codebooks, float* __restrict__ zq_out,
    float* __restrict__ out) {
    __shared__ float zcur[ND], resid[ND], zqsum[ND], ssq[ND];
    __shared__ float sDw[16];
    __shared__ int   sKw[16];
    __shared__ int   sBest;
    int t = threadIdx.x, lane = t & 63, wv = t >> 6;
    const float* img = latents + (size_t)latent_idx[0] * (NS * ND);
    if (t < ND) { resid[t] = 0.f; zqsum[t] = 0.f; }
    __syncthreads();
    float lossAcc = 0.f;   // thread 0 only
    for (int s = 0; s < NS; s++) {
        if (t < ND) {
            float iv = img[s * ND + t];
            float r  = resid[t] + iv;
            resid[t] = r;
            zcur[t]  = (s == 0) ? iv : (r - zqsum[t]);
        }
        __syncthreads();
        float zz = 0.f;
#pragma unroll
        for (int d = 0; d < ND; d++) { float z = zcur[d]; zz += z * z; }
        const float4* e4 = (const float4*)(codebooks + ((size_t)s * NK + t) * ND);
        float dot = 0.f, ee = 0.f;
#pragma unroll
        for (int i = 0; i < 16; i++) {
            float4 v = e4[i];
            dot += zcur[4 * i + 0] * v.x; dot += zcur[4 * i + 1] * v.y;
            dot += zcur[4 * i + 2] * v.z; dot += zcur[4 * i + 3] * v.w;
            ee  += v.x * v.x; ee += v.y * v.y; ee += v.z * v.z; ee += v.w * v.w;
        }
        float dmin = zz - 2.0f * dot + ee;
        int   kmin = t;
#pragma unroll
        for (int m = 1; m < 64; m <<= 1) {
            float d2 = __shfl_xor(dmin, m);
            int   k2 = __shfl_xor(kmin, m);
            if (d2 < dmin || (d2 == dmin && k2 < kmin)) { dmin = d2; kmin = k2; }
        }
        if (lane == 0) { sDw[wv] = dmin; sKw[wv] = kmin; }
        __syncthreads();
        if (t == 0) {
            float bd = sDw[0]; int bk = sKw[0];
            for (int w = 1; w < 16; w++) {
                float d2 = sDw[w]; int k2 = sKw[w];
                if (d2 < bd || (d2 == bd && k2 < bk)) { bd = d2; bk = k2; }
            }
            sBest = bk;
            out[NB * NV + s] = (float)bk;
        }
        __syncthreads();
        int best = sBest;
        const float* eb = codebooks + ((size_t)s * NK + best) * ND;
        if (t < ND) {
            float zq = eb[t];
            float d  = zq - zcur[t];
            ssq[t]   = d * d;
            zqsum[t] = zqsum[t] + (zq + (zcur[t] - zq));   // z_q_st forward (exact ref arith)
        }
        __syncthreads();
        if (t == 0) {
            float sum = 0.f;
            for (int d = 0; d < ND; d++) sum += ssq[d];
            lossAcc += 0.25f * (sum / (float)ND);
        }
    }
    if (t < ND) zq_out[t] = zqsum[t];
    if (t == 0) out[NB * NV + NS] = lossAcc;
}

// ---------------------------------------------------------------------------
// betas fused with decoder biases (fp32)
// ---------------------------------------------------------------------------
__global__ __launch_bounds__(256) void betas_kernel(
    const float* __restrict__ zq, const float* __restrict__ mod_W,
    const float* __restrict__ mod_b, const float* __restrict__ b0,
    const float* __restrict__ bh, float* __restrict__ bb) {
    int g = blockIdx.x * 256 + threadIdx.x;   // < 5120
    int l = g >> 10, n = g & 1023;
    float acc = mod_b[g];
    for (int d = 0; d < ND; d++) acc += zq[d] * mod_W[(size_t)(l * ND + d) * NH + n];
    acc += (l == 0) ? b0[n] : bh[(size_t)(l - 1) * NH + n];
    bb[g] = acc;
}

// ---------------------------------------------------------------------------
// out init: values[m][v] = bout[v] (atomic-add target for the fused layer)
// ---------------------------------------------------------------------------
__global__ __launch_bounds__(256) void init_out_kernel(
    const float* __restrict__ bout, float* __restrict__ out) {
    int g = blockIdx.x * 256 + threadIdx.x;   // < NB*NV
    out[g] = bout[g % NV];
}

// ---------------------------------------------------------------------------
// Weight prep: fp32 [Ks][1024] -> fp8 e4m3 transposed [1024][Kp], value*64
// (the x64 is undone exactly by the MFMA e8m0 scale 2^-6; keeps W out of the
// fp8 denormal range). Zero-pad k>=Ks.
// ---------------------------------------------------------------------------
__global__ __launch_bounds__(256) void prep_kernel(
    const float* __restrict__ src, u8* __restrict__ dst, int Ks, int Kp) {
    __shared__ float tile[32][33];
    src += (size_t)blockIdx.z * Ks * NH;
    dst += (size_t)blockIdx.z * NH * Kp;
    int k0 = blockIdx.x * 32, n0 = blockIdx.y * 32;
    int tx = threadIdx.x, ty = threadIdx.y;   // (32, 8)
    for (int i = 0; i < 4; i++) {
        int k = k0 + ty + i * 8;
        int n = n0 + tx;
        tile[ty + i * 8][tx] = (k < Ks) ? src[(size_t)k * NH + n] : 0.0f;
    }
    __syncthreads();
    for (int i = 0; i < 4; i++) {
        int n = n0 + ty + i * 8;
        int k = k0 + tx;
        dst[(size_t)n * Kp + k] = to_fp8(tile[tx][ty + i * 8] * 64.0f);
    }
}

// ---------------------------------------------------------------------------
// Positional encoding -> fp8 [Bc][128] (4 elems/thread packed into one int)
// ---------------------------------------------------------------------------
__device__ __forceinline__ float pe_val(const float* coords, int m, int k) {
    if (k < 2) return coords[m * 2 + k];
    if (k >= NIN) return 0.0f;
    int u = k - 2;
    int f = u >> 2, r = u & 3;
    float c = coords[m * 2 + (r & 1)];
    float a = c * __builtin_ldexpf(3.14159274101257324f, f);
    return (r < 2) ? sinf(a) : cosf(a);
}

__global__ __launch_bounds__(256) void pe_kernel(
    const float* __restrict__ coords, u8* __restrict__ pe) {
    int g = blockIdx.x * 256 + threadIdx.x;   // < Bc*32
    int m = g >> 5, k4 = (g & 31) * 4;
    float v0 = pe_val(coords, m, k4 + 0);
    float v1 = pe_val(coords, m, k4 + 1);
    float v2 = pe_val(coords, m, k4 + 2);
    float v3 = pe_val(coords, m, k4 + 3);
    int p = __builtin_amdgcn_cvt_pk_fp8_f32(v0, v1, 0, false);
    p     = __builtin_amdgcn_cvt_pk_fp8_f32(v2, v3, p, true);
    ((int*)pe)[g] = p;
}

// ---------------------------------------------------------------------------
// MX-fp8 MFMA GEMM: acc = A[M][K] @ W^T[1024][K] (+bb), fp8 e4m3 in, fp32 acc.
// mfma_scale_f32_16x16x128_f8f6f4, uniform e8m0 scales: A=2^0 (0x7f),
// W=2^-6 (0x79, undoes the x64 prep scale exactly). 128x128 tile, BK=128,
// 4 waves 2x2, wave tile 64x64. LDS rows = 8 x 16B chunks, source-XOR-swizzle
// c^(r&7) -> frag ds_read_b128 hits all 8 chunk-columns evenly (8 lanes each,
// balanced = conflict-free). Staging: global_load_lds width=16 (m104-safe:
// linear LDS dest, permuted global source). XCD-residue decode kept (R4).
// MODE 0: O = relu(acc+bb) stored fp8 (4B packed).
// MODE 1: out[m][v] += relu(acc+bb).Wout[n][v], q-lane shfl reduce + atomicAdd.
// ---------------------------------------------------------------------------
template <int MODE, int KT>
__global__ __launch_bounds__(256, 4) void gemm_kernel(
    const u8* __restrict__ A, const u8* __restrict__ W,
    const float* __restrict__ bb, u8* __restrict__ O,
    const float* __restrict__ Wout, float* __restrict__ out, int Mb) {
    __shared__ __align__(16) u8 sA[128 * 128];
    __shared__ __align__(16) u8 sW[128 * 128];
    int t   = threadIdx.x;
    int fid = blockIdx.x;
    int xcd = fid & 7;
    int j8  = fid >> 3;                 // 0..Mb-1
    int bn  = j8 & 7;                   // fastest within an XCD
    int bm  = xcd * (Mb >> 3) + (j8 >> 3);
    int lane = t & 63, wv = t >> 6;
    int wm   = wv >> 1, wn = wv & 1;
    int q    = lane >> 4, r16 = lane & 15;
    int sw   = r16 & 7;                 // chunk swizzle for this lane's rows

    f32x4 acc[4][4];
    f32x4 zero = {0.f, 0.f, 0.f, 0.f};
    for (int i = 0; i < 4; i++)
        for (int j = 0; j < 4; j++) acc[i][j] = zero;

#pragma unroll 1
    for (int it = 0; it < (KT >> 7); it++) {
        int kb = it << 7;
        // stage 16KB A + 16KB W: 1024 16B-chunks each, 4 per thread per matrix
#pragma unroll
        for (int p = 0; p < 4; p++) {
            int g  = p * 256 + t;
            int r  = g >> 3;
            int c  = (g & 7) ^ (r & 7);    // swizzled source chunk
            load_lds16((const void*)(A + (size_t)(bm * 128 + r) * KT + kb + c * 16),
                       (void*)(sA + g * 16));
            load_lds16((const void*)(W + (size_t)(bn * 128 + r) * KT + kb + c * 16),
                       (void*)(sW + g * 16));
        }
        __syncthreads();

        i32x8 bfr[4];
#pragma unroll
        for (int j = 0; j < 4; j++) {
            int base = (wn * 64 + j * 16 + r16) * 8;
            i32x4 lo = *(const i32x4*)(sW + (base + ((2 * q + 0) ^ sw)) * 16);
            i32x4 hi = *(const i32x4*)(sW + (base + ((2 * q + 1) ^ sw)) * 16);
            bfr[j] = __builtin_shufflevector(lo, hi, 0, 1, 2, 3, 4, 5, 6, 7);
        }
#pragma unroll
        for (int i = 0; i < 4; i++) {
            int base = (wm * 64 + i * 16 + r16) * 8;
            i32x4 lo = *(const i32x4*)(sA + (base + ((2 * q + 0) ^ sw)) * 16);
            i32x4 hi = *(const i32x4*)(sA + (base + ((2 * q + 1) ^ sw)) * 16);
            i32x8 af = __builtin_shufflevector(lo, hi, 0, 1, 2, 3, 4, 5, 6, 7);
            // swapped operands: D rows (q*4+r) = n-dim(j), cols (r16) = m-dim(i)
#pragma unroll
            for (int j = 0; j < 4; j++)
                acc[i][j] = __builtin_amdgcn_mfma_scale_f32_16x16x128_f8f6f4(
                    bfr[j], af, acc[i][j], 0, 0,
                    0, 0x79797979,    // scale src0 (W): 2^-6
                    0, 0x7f7f7f7f);   // scale src1 (A): 2^0
        }
        __syncthreads();
    }

    // lane element (i,j,r):  m = bm*128+wm*64+i*16+r16,  n = bn*128+wn*64+j*16+q*4+r
    if constexpr (MODE == 0) {
#pragma unroll
        for (int j = 0; j < 4; j++) {
            int nb = bn * 128 + wn * 64 + j * 16 + q * 4;
            f32x4 b4 = *(const f32x4*)(bb + nb);
#pragma unroll
            for (int i = 0; i < 4; i++) {
                int m = bm * 128 + wm * 64 + i * 16 + r16;
                float v0 = fmaxf(acc[i][j][0] + b4[0], 0.0f);
                float v1 = fmaxf(acc[i][j][1] + b4[1], 0.0f);
                float v2 = fmaxf(acc[i][j][2] + b4[2], 0.0f);
                float v3 = fmaxf(acc[i][j][3] + b4[3], 0.0f);
                int p = __builtin_amdgcn_cvt_pk_fp8_f32(v0, v1, 0, false);
                p     = __builtin_amdgcn_cvt_pk_fp8_f32(v2, v3, p, true);
                *(int*)(O + (size_t)m * NH + nb) = p;
            }
        }
    } else {
#pragma unroll
        for (int i = 0; i < 4; i++) {
            float p0 = 0.f, p1 = 0.f, p2 = 0.f;
#pragma unroll
            for (int j = 0; j < 4; j++) {
                int nb = bn * 128 + wn * 64 + j * 16 + q * 4;
                f32x4 b4 = *(const f32x4*)(bb + nb);
#pragma unroll
                for (int r = 0; r < 4; r++) {
                    float val = fmaxf(acc[i][j][r] + b4[r], 0.0f);
                    const float* w = Wout + (size_t)(nb + r) * NV;
                    p0 += val * w[0]; p1 += val * w[1]; p2 += val * w[2];
                }
            }
            // reduce over the 4 q-lanes (lane bits 4,5) holding the same m
            p0 += __shfl_xor(p0, 16); p0 += __shfl_xor(p0, 32);
            p1 += __shfl_xor(p1, 16); p1 += __shfl_xor(p1, 32);
            p2 += __shfl_xor(p2, 16); p2 += __shfl_xor(p2, 32);
            if (q == 0) {
                int m = bm * 128 + wm * 64 + i * 16 + r16;
                atomicAdd(&out[(size_t)m * NV + 0], p0);
                atomicAdd(&out[(size_t)m * NV + 1], p1);
                atomicAdd(&out[(size_t)m * NV + 2], p2);
            }
        }
    }
}

// ---------------------------------------------------------------------------
extern "C" void kernel_launch(void* const* d_in, const int* in_sizes, int n_in,
                              void* d_out, int out_size, void* d_ws, size_t ws_size,
                              hipStream_t stream) {
    const float* coords     = (const float*)d_in[0];
    const int*   latent_idx = (const int*)d_in[1];
    const float* latents    = (const float*)d_in[2];
    const float* codebooks  = (const float*)d_in[3];
    const float* mod_W      = (const float*)d_in[4];
    const float* mod_b      = (const float*)d_in[5];
    const float* dec_W0     = (const float*)d_in[6];
    const float* dec_b0     = (const float*)d_in[7];
    const float* dec_Wh     = (const float*)d_in[8];
    const float* dec_bh     = (const float*)d_in[9];
    const float* dec_Wout   = (const float*)d_in[10];
    const float* dec_bout   = (const float*)d_in[11];
    float* out = (float*)d_out;

    // ---- workspace layout (fixed part ~4.35 MB) ----
    char* wsb = (char*)d_ws;
    float* zq  = (float*)(wsb + 0);                        //      256 B
    float* bb  = (float*)(wsb + 256);                      //   20,480 B
    u8*    W0T = (u8*)(wsb + 20736);                       //  131,072 B  [1024][128]
    u8*    WhT = (u8*)(wsb + 151808);                      // 4,194,304 B [4][1024][1024]
    const size_t fixed_end = 4346368;                      // 256-aligned

    // adaptive chunk: cap 65536 (single chunk, ws ~139 MB), halve until fits;
    // floor 1024 so Mb%8==0. Deterministic in ws_size (capture-safe).
    int Bc = 65536;
    while (Bc > 1024 && fixed_end + 2 * (size_t)Bc * NH > ws_size)
        Bc >>= 1;
    int Mb = Bc / 128;

    u8* hA = (u8*)(wsb + fixed_end);                       // [Bc][1024] fp8
    u8* hB = hA + (size_t)Bc * NH;                         // [Bc][1024] fp8
    u8* pe = hB;   // pe [Bc][128] fp8 aliases hB (dead before layer-1 writes hB)

    // ---- one-time (per call) small kernels ----
    vq_kernel<<<1, 1024, 0, stream>>>(latents, latent_idx, codebooks, zq, out);
    betas_kernel<<<20, 256, 0, stream>>>(zq, mod_W, mod_b, dec_b0, dec_bh, bb);
    init_out_kernel<<<(NB * NV) / 256, 256, 0, stream>>>(dec_bout, out);
    prep_kernel<<<dim3(4, 32, 1), dim3(32, 8), 0, stream>>>(dec_W0, W0T, NIN, K0P);
    prep_kernel<<<dim3(32, 32, 4), dim3(32, 8), 0, stream>>>(dec_Wh, WhT, NH, NH);

    // ---- chunked 5-layer MLP, output layer fused into the last GEMM ----
    for (int c0 = 0; c0 < NB; c0 += Bc) {
        pe_kernel<<<(Bc * 32) / 256, 256, 0, stream>>>(coords + (size_t)c0 * NC, pe);
        gemm_kernel<0, K0P><<<8 * Mb, 256, 0, stream>>>(
            pe, W0T, bb + 0 * NH, hA, nullptr, nullptr, Mb);
        gemm_kernel<0, NH><<<8 * Mb, 256, 0, stream>>>(
            hA, WhT + 0 * (size_t)NH * NH, bb + 1 * NH, hB, nullptr, nullptr, Mb);
        gemm_kernel<0, NH><<<8 * Mb, 256, 0, stream>>>(
            hB, WhT + 1 * (size_t)NH * NH, bb + 2 * NH, hA, nullptr, nullptr, Mb);
        gemm_kernel<0, NH><<<8 * Mb, 256, 0, stream>>>(
            hA, WhT + 2 * (size_t)NH * NH, bb + 3 * NH, hB, nullptr, nullptr, Mb);
        gemm_kernel<1, NH><<<8 * Mb, 256, 0, stream>>>(
            hB, WhT + 3 * (size_t)NH * NH, bb + 4 * NH, nullptr,
            dec_Wout, out + (size_t)c0 * NV, Mb);
    }
}

// Round 9
// 605.212 us; speedup vs baseline: 3.6006x; 1.1571x over previous
//
#include <hip/hip_runtime.h>
#include <hip/hip_bf16.h>
#include <stdint.h>

// ---- problem constants ----
#define NB   65536      // batch points
#define NC   2
#define NV   3
#define ND   64
#define NK   1024       // codebook entries
#define NS   4
#define NH   1024
#define NL   5
#define NF   25
#define NIN  102
#define K0P  128        // padded layer-0 K

typedef float f32x4 __attribute__((ext_vector_type(4)));
typedef int   i32x4 __attribute__((ext_vector_type(4)));
typedef int   i32x8 __attribute__((ext_vector_type(8)));
typedef unsigned char u8;

__device__ __forceinline__ void load_lds16(const void* g, void* l) {
    __builtin_amdgcn_global_load_lds(
        (const __attribute__((address_space(1))) void*)g,
        (__attribute__((address_space(3))) void*)l,
        16, 0, 0);
}

// fp8 e4m3 scalar convert (RNE, saturating): low byte of cvt_pk
__device__ __forceinline__ u8 to_fp8(float x) {
    return (u8)(__builtin_amdgcn_cvt_pk_fp8_f32(x, 0.0f, 0, false) & 0xff);
}

// ---------------------------------------------------------------------------
// VQ kernel: single block, 1024 threads (one codebook row per thread). fp32.
// ---------------------------------------------------------------------------
__global__ __launch_bounds__(1024) void vq_kernel(
    const float* __restrict__ latents, const int* __restrict__ latent_idx,
    const float* __restrict__ codebooks, float* __restrict__ zq_out,
    float* __restrict__ out) {
    __shared__ float zcur[ND], resid[ND], zqsum[ND], ssq[ND];
    __shared__ float sDw[16];
    __shared__ int   sKw[16];
    __shared__ int   sBest;
    int t = threadIdx.x, lane = t & 63, wv = t >> 6;
    const float* img = latents + (size_t)latent_idx[0] * (NS * ND);
    if (t < ND) { resid[t] = 0.f; zqsum[t] = 0.f; }
    __syncthreads();
    float lossAcc = 0.f;   // thread 0 only
    for (int s = 0; s < NS; s++) {
        if (t < ND) {
            float iv = img[s * ND + t];
            float r  = resid[t] + iv;
            resid[t] = r;
            zcur[t]  = (s == 0) ? iv : (r - zqsum[t]);
        }
        __syncthreads();
        float zz = 0.f;
#pragma unroll
        for (int d = 0; d < ND; d++) { float z = zcur[d]; zz += z * z; }
        const float4* e4 = (const float4*)(codebooks + ((size_t)s * NK + t) * ND);
        float dot = 0.f, ee = 0.f;
#pragma unroll
        for (int i = 0; i < 16; i++) {
            float4 v = e4[i];
            dot += zcur[4 * i + 0] * v.x; dot += zcur[4 * i + 1] * v.y;
            dot += zcur[4 * i + 2] * v.z; dot += zcur[4 * i + 3] * v.w;
            ee  += v.x * v.x; ee += v.y * v.y; ee += v.z * v.z; ee += v.w * v.w;
        }
        float dmin = zz - 2.0f * dot + ee;
        int   kmin = t;
#pragma unroll
        for (int m = 1; m < 64; m <<= 1) {
            float d2 = __shfl_xor(dmin, m);
            int   k2 = __shfl_xor(kmin, m);
            if (d2 < dmin || (d2 == dmin && k2 < kmin)) { dmin = d2; kmin = k2; }
        }
        if (lane == 0) { sDw[wv] = dmin; sKw[wv] = kmin; }
        __syncthreads();
        if (t == 0) {
            float bd = sDw[0]; int bk = sKw[0];
            for (int w = 1; w < 16; w++) {
                float d2 = sDw[w]; int k2 = sKw[w];
                if (d2 < bd || (d2 == bd && k2 < bk)) { bd = d2; bk = k2; }
            }
            sBest = bk;
            out[NB * NV + s] = (float)bk;
        }
        __syncthreads();
        int best = sBest;
        const float* eb = codebooks + ((size_t)s * NK + best) * ND;
        if (t < ND) {
            float zq = eb[t];
            float d  = zq - zcur[t];
            ssq[t]   = d * d;
            zqsum[t] = zqsum[t] + (zq + (zcur[t] - zq));   // z_q_st forward (exact ref arith)
        }
        __syncthreads();
        if (t == 0) {
            float sum = 0.f;
            for (int d = 0; d < ND; d++) sum += ssq[d];
            lossAcc += 0.25f * (sum / (float)ND);
        }
    }
    if (t < ND) zq_out[t] = zqsum[t];
    if (t == 0) out[NB * NV + NS] = lossAcc;
}

// ---------------------------------------------------------------------------
// betas fused with decoder biases (fp32)
// ---------------------------------------------------------------------------
__global__ __launch_bounds__(256) void betas_kernel(
    const float* __restrict__ zq, const float* __restrict__ mod_W,
    const float* __restrict__ mod_b, const float* __restrict__ b0,
    const float* __restrict__ bh, float* __restrict__ bb) {
    int g = blockIdx.x * 256 + threadIdx.x;   // < 5120
    int l = g >> 10, n = g & 1023;
    float acc = mod_b[g];
    for (int d = 0; d < ND; d++) acc += zq[d] * mod_W[(size_t)(l * ND + d) * NH + n];
    acc += (l == 0) ? b0[n] : bh[(size_t)(l - 1) * NH + n];
    bb[g] = acc;
}

// ---------------------------------------------------------------------------
// out init: values[m][v] = bout[v] (atomic-add target for the fused layer)
// ---------------------------------------------------------------------------
__global__ __launch_bounds__(256) void init_out_kernel(
    const float* __restrict__ bout, float* __restrict__ out) {
    int g = blockIdx.x * 256 + threadIdx.x;   // < NB*NV
    out[g] = bout[g % NV];
}

// ---------------------------------------------------------------------------
// Weight prep: fp32 [Ks][1024] -> fp8 e4m3 transposed [1024][Kp], value*64
// (undone exactly by the MFMA e8m0 scale 2^-6). Zero-pad k>=Ks.
// ---------------------------------------------------------------------------
__global__ __launch_bounds__(256) void prep_kernel(
    const float* __restrict__ src, u8* __restrict__ dst, int Ks, int Kp) {
    __shared__ float tile[32][33];
    src += (size_t)blockIdx.z * Ks * NH;
    dst += (size_t)blockIdx.z * NH * Kp;
    int k0 = blockIdx.x * 32, n0 = blockIdx.y * 32;
    int tx = threadIdx.x, ty = threadIdx.y;   // (32, 8)
    for (int i = 0; i < 4; i++) {
        int k = k0 + ty + i * 8;
        int n = n0 + tx;
        tile[ty + i * 8][tx] = (k < Ks) ? src[(size_t)k * NH + n] : 0.0f;
    }
    __syncthreads();
    for (int i = 0; i < 4; i++) {
        int n = n0 + ty + i * 8;
        int k = k0 + tx;
        dst[(size_t)n * Kp + k] = to_fp8(tile[tx][ty + i * 8] * 64.0f);
    }
}

// ---------------------------------------------------------------------------
// Positional encoding -> fp8 [Bc][128] (4 elems/thread packed into one int)
// ---------------------------------------------------------------------------
__device__ __forceinline__ float pe_val(const float* coords, int m, int k) {
    if (k < 2) return coords[m * 2 + k];
    if (k >= NIN) return 0.0f;
    int u = k - 2;
    int f = u >> 2, r = u & 3;
    float c = coords[m * 2 + (r & 1)];
    float a = c * __builtin_ldexpf(3.14159274101257324f, f);
    return (r < 2) ? sinf(a) : cosf(a);
}

__global__ __launch_bounds__(256) void pe_kernel(
    const float* __restrict__ coords, u8* __restrict__ pe) {
    int g = blockIdx.x * 256 + threadIdx.x;   // < Bc*32
    int m = g >> 5, k4 = (g & 31) * 4;
    float v0 = pe_val(coords, m, k4 + 0);
    float v1 = pe_val(coords, m, k4 + 1);
    float v2 = pe_val(coords, m, k4 + 2);
    float v3 = pe_val(coords, m, k4 + 3);
    int p = __builtin_amdgcn_cvt_pk_fp8_f32(v0, v1, 0, false);
    p     = __builtin_amdgcn_cvt_pk_fp8_f32(v2, v3, p, true);
    ((int*)pe)[g] = p;
}

// ---------------------------------------------------------------------------
// MX-fp8 MFMA GEMM: acc = A[M][K] @ W^T[1024][K] (+bb), fp8 e4m3 in, fp32 acc.
// mfma_scale_f32_16x16x128_f8f6f4, uniform e8m0 scales (W 2^-6, A 2^0).
// 128x128 tile, BK=128, 4 waves 2x2, wave tile 64x64.
//
// R9 LDS swizzle: chunk c (16B) of row r stored at position
//   P = ((c&1)^(r&1))*4 + ((c>>1)^((r>>1)&3))
// so the fragment lo-read (k=q*32) hits bank-group
//   G = (r16&1)*4 + (q^((r16>>1)&3))
// -- BIT-IDENTICAL to the R3-R6 bf16 map measured at 0 conflicts (R8's
// c^(r&7) map cost exactly +4 cyc per b128: 2^23 conflicts/dispatch).
// Staging keeps lane-linear LDS dest (m104) and inverts P on the source side.
//
// MODE 0 epilogue: pack fp8 into padded LDS tile [128][132], barrier, read
// back lane-linear b128, store dwordx4 (full 64B lines) -- replaces R8's 16
// scattered 4B stores/lane (WRITE_SIZE 110 vs 67 MB ideal).
// MODE 1: out[m][v] += relu(acc+bb).Wout[n][v], q-lane shfl reduce + atomicAdd.
// ---------------------------------------------------------------------------
template <int MODE, int KT>
__global__ __launch_bounds__(256, 4) void gemm_kernel(
    const u8* __restrict__ A, const u8* __restrict__ W,
    const float* __restrict__ bb, u8* __restrict__ O,
    const float* __restrict__ Wout, float* __restrict__ out, int Mb) {
    __shared__ __align__(16) u8 smem[32768];
    u8* sA = smem;              // [128 rows][128B], swizzled
    u8* sW = smem + 16384;
    int t   = threadIdx.x;
    int fid = blockIdx.x;
    int xcd = fid & 7;
    int j8  = fid >> 3;                 // 0..Mb-1
    int bn  = j8 & 7;                   // fastest within an XCD
    int bm  = xcd * (Mb >> 3) + (j8 >> 3);
    int lane = t & 63, wv = t >> 6;
    int wm   = wv >> 1, wn = wv & 1;
    int q    = lane >> 4, r16 = lane & 15;
    int s2   = (r16 >> 1) & 3, par = r16 & 1;
    int plo  = par * 4 + (q ^ s2);          // position of k-chunk 2q
    int phi  = (par ^ 1) * 4 + (q ^ s2);    // position of k-chunk 2q+1

    f32x4 acc[4][4];
    f32x4 zero = {0.f, 0.f, 0.f, 0.f};
    for (int i = 0; i < 4; i++)
        for (int j = 0; j < 4; j++) acc[i][j] = zero;

#pragma unroll 1
    for (int it = 0; it < (KT >> 7); it++) {
        int kb = it << 7;
        // stage 16KB A + 16KB W; LDS dest lane-linear, source chunk = P^-1
#pragma unroll
        for (int p = 0; p < 4; p++) {
            int g  = p * 256 + t;
            int r  = g >> 3, P = g & 7;
            int c  = (((P & 3) ^ ((r >> 1) & 3)) << 1) | ((P >> 2) ^ (r & 1));
            load_lds16((const void*)(A + (size_t)(bm * 128 + r) * KT + kb + c * 16),
                       (void*)(sA + g * 16));
            load_lds16((const void*)(W + (size_t)(bn * 128 + r) * KT + kb + c * 16),
                       (void*)(sW + g * 16));
        }
        __syncthreads();

        i32x8 bfr[4];
#pragma unroll
        for (int j = 0; j < 4; j++) {
            int base = (wn * 64 + j * 16 + r16) * 128;
            i32x4 lo = *(const i32x4*)(sW + base + plo * 16);
            i32x4 hi = *(const i32x4*)(sW + base + phi * 16);
            bfr[j] = __builtin_shufflevector(lo, hi, 0, 1, 2, 3, 4, 5, 6, 7);
        }
#pragma unroll
        for (int i = 0; i < 4; i++) {
            int base = (wm * 64 + i * 16 + r16) * 128;
            i32x4 lo = *(const i32x4*)(sA + base + plo * 16);
            i32x4 hi = *(const i32x4*)(sA + base + phi * 16);
            i32x8 af = __builtin_shufflevector(lo, hi, 0, 1, 2, 3, 4, 5, 6, 7);
            // swapped operands: D rows (q*4+r) = n-dim(j), cols (r16) = m-dim(i)
#pragma unroll
            for (int j = 0; j < 4; j++)
                acc[i][j] = __builtin_amdgcn_mfma_scale_f32_16x16x128_f8f6f4(
                    bfr[j], af, acc[i][j], 0, 0,
                    0, 0x79797979,    // scale src0 (W): 2^-6
                    0, 0x7f7f7f7f);   // scale src1 (A): 2^0
        }
        __syncthreads();
    }

    // lane element (i,j,r):  m = bm*128+wm*64+i*16+r16,  n = bn*128+wn*64+j*16+q*4+r
    if constexpr (MODE == 0) {
        // pack into padded LDS tile [128][132B] (aliases sA/sW -- safe after
        // the loop's trailing barrier), then coalesced dwordx4 stores.
        u8* eb = smem;
        int ml = wm * 64 + r16;
#pragma unroll
        for (int i = 0; i < 4; i++) {
#pragma unroll
            for (int j = 0; j < 4; j++) {
                int nl = wn * 64 + j * 16 + q * 4;
                f32x4 b4 = *(const f32x4*)(bb + bn * 128 + nl);
                float v0 = fmaxf(acc[i][j][0] + b4[0], 0.0f);
                float v1 = fmaxf(acc[i][j][1] + b4[1], 0.0f);
                float v2 = fmaxf(acc[i][j][2] + b4[2], 0.0f);
                float v3 = fmaxf(acc[i][j][3] + b4[3], 0.0f);
                int p = __builtin_amdgcn_cvt_pk_fp8_f32(v0, v1, 0, false);
                p     = __builtin_amdgcn_cvt_pk_fp8_f32(v2, v3, p, true);
                *(int*)(eb + (ml + i * 16) * 132 + nl) = p;
            }
        }
        __syncthreads();
#pragma unroll
        for (int rd = 0; rd < 4; rd++) {
            int g2  = rd * 256 + t;
            int row = g2 >> 3, cc = g2 & 7;
            i32x4 v = *(const i32x4*)(eb + row * 132 + cc * 16);
            *(i32x4*)(O + (size_t)(bm * 128 + row) * NH + bn * 128 + cc * 16) = v;
        }
    } else {
#pragma unroll
        for (int i = 0; i < 4; i++) {
            float p0 = 0.f, p1 = 0.f, p2 = 0.f;
#pragma unroll
            for (int j = 0; j < 4; j++) {
                int nb = bn * 128 + wn * 64 + j * 16 + q * 4;
                f32x4 b4 = *(const f32x4*)(bb + nb);
#pragma unroll
                for (int r = 0; r < 4; r++) {
                    float val = fmaxf(acc[i][j][r] + b4[r], 0.0f);
                    const float* w = Wout + (size_t)(nb + r) * NV;
                    p0 += val * w[0]; p1 += val * w[1]; p2 += val * w[2];
                }
            }
            // reduce over the 4 q-lanes (lane bits 4,5) holding the same m
            p0 += __shfl_xor(p0, 16); p0 += __shfl_xor(p0, 32);
            p1 += __shfl_xor(p1, 16); p1 += __shfl_xor(p1, 32);
            p2 += __shfl_xor(p2, 16); p2 += __shfl_xor(p2, 32);
            if (q == 0) {
                int m = bm * 128 + wm * 64 + i * 16 + r16;
                atomicAdd(&out[(size_t)m * NV + 0], p0);
                atomicAdd(&out[(size_t)m * NV + 1], p1);
                atomicAdd(&out[(size_t)m * NV + 2], p2);
            }
        }
    }
}

// ---------------------------------------------------------------------------
extern "C" void kernel_launch(void* const* d_in, const int* in_sizes, int n_in,
                              void* d_out, int out_size, void* d_ws, size_t ws_size,
                              hipStream_t stream) {
    const float* coords     = (const float*)d_in[0];
    const int*   latent_idx = (const int*)d_in[1];
    const float* latents    = (const float*)d_in[2];
    const float* codebooks  = (const float*)d_in[3];
    const float* mod_W      = (const float*)d_in[4];
    const float* mod_b      = (const float*)d_in[5];
    const float* dec_W0     = (const float*)d_in[6];
    const float* dec_b0     = (const float*)d_in[7];
    const float* dec_Wh     = (const float*)d_in[8];
    const float* dec_bh     = (const float*)d_in[9];
    const float* dec_Wout   = (const float*)d_in[10];
    const float* dec_bout   = (const float*)d_in[11];
    float* out = (float*)d_out;

    // ---- workspace layout (fixed part ~4.35 MB) ----
    char* wsb = (char*)d_ws;
    float* zq  = (float*)(wsb + 0);                        //      256 B
    float* bb  = (float*)(wsb + 256);                      //   20,480 B
    u8*    W0T = (u8*)(wsb + 20736);                       //  131,072 B  [1024][128]
    u8*    WhT = (u8*)(wsb + 151808);                      // 4,194,304 B [4][1024][1024]
    const size_t fixed_end = 4346368;                      // 256-aligned

    // adaptive chunk: cap 65536 (single chunk, ws ~139 MB), halve until fits;
    // floor 1024 so Mb%8==0. Deterministic in ws_size (capture-safe).
    int Bc = 65536;
    while (Bc > 1024 && fixed_end + 2 * (size_t)Bc * NH > ws_size)
        Bc >>= 1;
    int Mb = Bc / 128;

    u8* hA = (u8*)(wsb + fixed_end);                       // [Bc][1024] fp8
    u8* hB = hA + (size_t)Bc * NH;                         // [Bc][1024] fp8
    u8* pe = hB;   // pe [Bc][128] fp8 aliases hB (dead before layer-1 writes hB)

    // ---- one-time (per call) small kernels ----
    vq_kernel<<<1, 1024, 0, stream>>>(latents, latent_idx, codebooks, zq, out);
    betas_kernel<<<20, 256, 0, stream>>>(zq, mod_W, mod_b, dec_b0, dec_bh, bb);
    init_out_kernel<<<(NB * NV) / 256, 256, 0, stream>>>(dec_bout, out);
    prep_kernel<<<dim3(4, 32, 1), dim3(32, 8), 0, stream>>>(dec_W0, W0T, NIN, K0P);
    prep_kernel<<<dim3(32, 32, 4), dim3(32, 8), 0, stream>>>(dec_Wh, WhT, NH, NH);

    // ---- chunked 5-layer MLP, output layer fused into the last GEMM ----
    for (int c0 = 0; c0 < NB; c0 += Bc) {
        pe_kernel<<<(Bc * 32) / 256, 256, 0, stream>>>(coords + (size_t)c0 * NC, pe);
        gemm_kernel<0, K0P><<<8 * Mb, 256, 0, stream>>>(
            pe, W0T, bb + 0 * NH, hA, nullptr, nullptr, Mb);
        gemm_kernel<0, NH><<<8 * Mb, 256, 0, stream>>>(
            hA, WhT + 0 * (size_t)NH * NH, bb + 1 * NH, hB, nullptr, nullptr, Mb);
        gemm_kernel<0, NH><<<8 * Mb, 256, 0, stream>>>(
            hB, WhT + 1 * (size_t)NH * NH, bb + 2 * NH, hA, nullptr, nullptr, Mb);
        gemm_kernel<0, NH><<<8 * Mb, 256, 0, stream>>>(
            hA, WhT + 2 * (size_t)NH * NH, bb + 3 * NH, hB, nullptr, nullptr, Mb);
        gemm_kernel<1, NH><<<8 * Mb, 256, 0, stream>>>(
            hB, WhT + 3 * (size_t)NH * NH, bb + 4 * NH, nullptr,
            dec_Wout, out + (size_t)c0 * NV, Mb);
    }
}

// Round 10
// 516.329 us; speedup vs baseline: 4.2204x; 1.1721x over previous
//
#include <hip/hip_runtime.h>
#include <hip/hip_bf16.h>
#include <stdint.h>

// ---- problem constants ----
#define NB   65536      // batch points
#define NC   2
#define NV   3
#define ND   64
#define NK   1024       // codebook entries
#define NS   4
#define NH   1024
#define NL   5
#define NF   25
#define NIN  102
#define K0P  128        // padded layer-0 K

typedef float f32x4 __attribute__((ext_vector_type(4)));
typedef int   i32x4 __attribute__((ext_vector_type(4)));
typedef int   i32x8 __attribute__((ext_vector_type(8)));
typedef unsigned char u8;

__device__ __forceinline__ void load_lds16(const void* g, void* l) {
    __builtin_amdgcn_global_load_lds(
        (const __attribute__((address_space(1))) void*)g,
        (__attribute__((address_space(3))) void*)l,
        16, 0, 0);
}

// fp8 e4m3 scalar convert (RNE, saturating): low byte of cvt_pk
__device__ __forceinline__ u8 to_fp8(float x) {
    return (u8)(__builtin_amdgcn_cvt_pk_fp8_f32(x, 0.0f, 0, false) & 0xff);
}

// ---------------------------------------------------------------------------
// VQ kernel: single block, 1024 threads (one codebook row per thread). fp32.
// ---------------------------------------------------------------------------
__global__ __launch_bounds__(1024) void vq_kernel(
    const float* __restrict__ latents, const int* __restrict__ latent_idx,
    const float* __restrict__ codebooks, float* __restrict__ zq_out,
    float* __restrict__ out) {
    __shared__ float zcur[ND], resid[ND], zqsum[ND], ssq[ND];
    __shared__ float sDw[16];
    __shared__ int   sKw[16];
    __shared__ int   sBest;
    int t = threadIdx.x, lane = t & 63, wv = t >> 6;
    const float* img = latents + (size_t)latent_idx[0] * (NS * ND);
    if (t < ND) { resid[t] = 0.f; zqsum[t] = 0.f; }
    __syncthreads();
    float lossAcc = 0.f;   // thread 0 only
    for (int s = 0; s < NS; s++) {
        if (t < ND) {
            float iv = img[s * ND + t];
            float r  = resid[t] + iv;
            resid[t] = r;
            zcur[t]  = (s == 0) ? iv : (r - zqsum[t]);
        }
        __syncthreads();
        float zz = 0.f;
#pragma unroll
        for (int d = 0; d < ND; d++) { float z = zcur[d]; zz += z * z; }
        const float4* e4 = (const float4*)(codebooks + ((size_t)s * NK + t) * ND);
        float dot = 0.f, ee = 0.f;
#pragma unroll
        for (int i = 0; i < 16; i++) {
            float4 v = e4[i];
            dot += zcur[4 * i + 0] * v.x; dot += zcur[4 * i + 1] * v.y;
            dot += zcur[4 * i + 2] * v.z; dot += zcur[4 * i + 3] * v.w;
            ee  += v.x * v.x; ee += v.y * v.y; ee += v.z * v.z; ee += v.w * v.w;
        }
        float dmin = zz - 2.0f * dot + ee;
        int   kmin = t;
#pragma unroll
        for (int m = 1; m < 64; m <<= 1) {
            float d2 = __shfl_xor(dmin, m);
            int   k2 = __shfl_xor(kmin, m);
            if (d2 < dmin || (d2 == dmin && k2 < kmin)) { dmin = d2; kmin = k2; }
        }
        if (lane == 0) { sDw[wv] = dmin; sKw[wv] = kmin; }
        __syncthreads();
        if (t == 0) {
            float bd = sDw[0]; int bk = sKw[0];
            for (int w = 1; w < 16; w++) {
                float d2 = sDw[w]; int k2 = sKw[w];
                if (d2 < bd || (d2 == bd && k2 < bk)) { bd = d2; bk = k2; }
            }
            sBest = bk;
            out[NB * NV + s] = (float)bk;
        }
        __syncthreads();
        int best = sBest;
        const float* eb = codebooks + ((size_t)s * NK + best) * ND;
        if (t < ND) {
            float zq = eb[t];
            float d  = zq - zcur[t];
            ssq[t]   = d * d;
            zqsum[t] = zqsum[t] + (zq + (zcur[t] - zq));   // z_q_st forward (exact ref arith)
        }
        __syncthreads();
        if (t == 0) {
            float sum = 0.f;
            for (int d = 0; d < ND; d++) sum += ssq[d];
            lossAcc += 0.25f * (sum / (float)ND);
        }
    }
    if (t < ND) zq_out[t] = zqsum[t];
    if (t == 0) out[NB * NV + NS] = lossAcc;
}

// ---------------------------------------------------------------------------
// betas fused with decoder biases (fp32)
// ---------------------------------------------------------------------------
__global__ __launch_bounds__(256) void betas_kernel(
    const float* __restrict__ zq, const float* __restrict__ mod_W,
    const float* __restrict__ mod_b, const float* __restrict__ b0,
    const float* __restrict__ bh, float* __restrict__ bb) {
    int g = blockIdx.x * 256 + threadIdx.x;   // < 5120
    int l = g >> 10, n = g & 1023;
    float acc = mod_b[g];
    for (int d = 0; d < ND; d++) acc += zq[d] * mod_W[(size_t)(l * ND + d) * NH + n];
    acc += (l == 0) ? b0[n] : bh[(size_t)(l - 1) * NH + n];
    bb[g] = acc;
}

// ---------------------------------------------------------------------------
// out init: values[m][v] = bout[v] (atomic-add target for the fused layer)
// ---------------------------------------------------------------------------
__global__ __launch_bounds__(256) void init_out_kernel(
    const float* __restrict__ bout, float* __restrict__ out) {
    int g = blockIdx.x * 256 + threadIdx.x;   // < NB*NV
    out[g] = bout[g % NV];
}

// ---------------------------------------------------------------------------
// Weight prep: fp32 [Ks][1024] -> fp8 e4m3 transposed [1024][Kp], value*64
// (undone exactly by the MFMA e8m0 scale 2^-6). Zero-pad k>=Ks.
// ---------------------------------------------------------------------------
__global__ __launch_bounds__(256) void prep_kernel(
    const float* __restrict__ src, u8* __restrict__ dst, int Ks, int Kp) {
    __shared__ float tile[32][33];
    src += (size_t)blockIdx.z * Ks * NH;
    dst += (size_t)blockIdx.z * NH * Kp;
    int k0 = blockIdx.x * 32, n0 = blockIdx.y * 32;
    int tx = threadIdx.x, ty = threadIdx.y;   // (32, 8)
    for (int i = 0; i < 4; i++) {
        int k = k0 + ty + i * 8;
        int n = n0 + tx;
        tile[ty + i * 8][tx] = (k < Ks) ? src[(size_t)k * NH + n] : 0.0f;
    }
    __syncthreads();
    for (int i = 0; i < 4; i++) {
        int n = n0 + ty + i * 8;
        int k = k0 + tx;
        dst[(size_t)n * Kp + k] = to_fp8(tile[tx][ty + i * 8] * 64.0f);
    }
}

// ---------------------------------------------------------------------------
// Positional encoding -> fp8 [Bc][128] (4 elems/thread packed into one int)
// ---------------------------------------------------------------------------
__device__ __forceinline__ float pe_val(const float* coords, int m, int k) {
    if (k < 2) return coords[m * 2 + k];
    if (k >= NIN) return 0.0f;
    int u = k - 2;
    int f = u >> 2, r = u & 3;
    float c = coords[m * 2 + (r & 1)];
    float a = c * __builtin_ldexpf(3.14159274101257324f, f);
    return (r < 2) ? sinf(a) : cosf(a);
}

__global__ __launch_bounds__(256) void pe_kernel(
    const float* __restrict__ coords, u8* __restrict__ pe) {
    int g = blockIdx.x * 256 + threadIdx.x;   // < Bc*32
    int m = g >> 5, k4 = (g & 31) * 4;
    float v0 = pe_val(coords, m, k4 + 0);
    float v1 = pe_val(coords, m, k4 + 1);
    float v2 = pe_val(coords, m, k4 + 2);
    float v3 = pe_val(coords, m, k4 + 3);
    int p = __builtin_amdgcn_cvt_pk_fp8_f32(v0, v1, 0, false);
    p     = __builtin_amdgcn_cvt_pk_fp8_f32(v2, v3, p, true);
    ((int*)pe)[g] = p;
}

// ---------------------------------------------------------------------------
// MX-fp8 MFMA GEMM, R10: 256m x 128n block tile, 4 waves stacked in m,
// wave tile 64m x 128n (acc[4][8] = 128 VGPRs, bfr[8] preloaded = 64).
// Rationale: R9's 2x2 wave grid read every LDS byte twice (LDS the longest
// pipe at ~768 cyc/block-iter vs MFMA 512). 64x128 wave tile does 2x MFMA
// per W-byte: per block-iter-SIMD MFMA 1024 cyc vs LDS ~640 vs TCP ~768 ->
// MFMA-bound static model. __launch_bounds__(256,2): ~220 regs, 2 blocks/CU
// (LDS 48KB single-buffered). K-loop math/swizzle/scales identical to R9.
// LDS swizzle: chunk c of row r at P = ((c&1)^(r&1))*4 + ((c>>1)^((r>>1)&3)).
// MODE 0: relu(acc+bb) -> fp8, padded-LDS transpose, coalesced dwordx4.
// MODE 1: out[m][v] += relu(acc+bb).Wout[n][v], q-lane shfl + atomicAdd.
// ---------------------------------------------------------------------------
template <int MODE, int KT>
__global__ __launch_bounds__(256, 2) void gemm_kernel(
    const u8* __restrict__ A, const u8* __restrict__ W,
    const float* __restrict__ bb, u8* __restrict__ O,
    const float* __restrict__ Wout, float* __restrict__ out, int Mb) {
    __shared__ __align__(16) u8 smem[49152];
    u8* sA = smem;              // [256 rows][128B], swizzled (32 KB)
    u8* sW = smem + 32768;      // [128 rows][128B], swizzled (16 KB)
    int t   = threadIdx.x;
    int fid = blockIdx.x;
    int xcd = fid & 7;
    int j8  = fid >> 3;                 // 0..Mb-1
    int bn  = j8 & 7;                   // fastest within an XCD
    int bm  = xcd * (Mb >> 3) + (j8 >> 3);
    int lane = t & 63, wm = t >> 6;     // wave owns m-slice wm*64..+63
    int q    = lane >> 4, r16 = lane & 15;
    int s2   = (r16 >> 1) & 3, par = r16 & 1;
    int plo  = par * 4 + (q ^ s2);          // position of k-chunk 2q
    int phi  = (par ^ 1) * 4 + (q ^ s2);    // position of k-chunk 2q+1

    f32x4 acc[4][8];
    f32x4 zero = {0.f, 0.f, 0.f, 0.f};
    for (int i = 0; i < 4; i++)
        for (int j = 0; j < 8; j++) acc[i][j] = zero;

#pragma unroll 1
    for (int it = 0; it < (KT >> 7); it++) {
        int kb = it << 7;
        // stage 32KB A (2048 chunks) + 16KB W (1024 chunks); LDS dest
        // lane-linear (m104), source chunk = P^-1
#pragma unroll
        for (int p = 0; p < 8; p++) {
            int g = p * 256 + t;
            int r = g >> 3, P = g & 7;
            int c = (((P & 3) ^ ((r >> 1) & 3)) << 1) | ((P >> 2) ^ (r & 1));
            load_lds16((const void*)(A + (size_t)(bm * 256 + r) * KT + kb + c * 16),
                       (void*)(sA + g * 16));
        }
#pragma unroll
        for (int p = 0; p < 4; p++) {
            int g = p * 256 + t;
            int r = g >> 3, P = g & 7;
            int c = (((P & 3) ^ ((r >> 1) & 3)) << 1) | ((P >> 2) ^ (r & 1));
            load_lds16((const void*)(W + (size_t)(bn * 128 + r) * KT + kb + c * 16),
                       (void*)(sW + g * 16));
        }
        __syncthreads();

        i32x8 bfr[8];
#pragma unroll
        for (int j = 0; j < 8; j++) {
            int base = (j * 16 + r16) * 128;
            i32x4 lo = *(const i32x4*)(sW + base + plo * 16);
            i32x4 hi = *(const i32x4*)(sW + base + phi * 16);
            bfr[j] = __builtin_shufflevector(lo, hi, 0, 1, 2, 3, 4, 5, 6, 7);
        }
#pragma unroll
        for (int i = 0; i < 4; i++) {
            int base = (wm * 64 + i * 16 + r16) * 128;
            i32x4 lo = *(const i32x4*)(sA + base + plo * 16);
            i32x4 hi = *(const i32x4*)(sA + base + phi * 16);
            i32x8 af = __builtin_shufflevector(lo, hi, 0, 1, 2, 3, 4, 5, 6, 7);
            // swapped operands: D rows (q*4+r) = n-dim(j), cols (r16) = m-dim(i)
#pragma unroll
            for (int j = 0; j < 8; j++)
                acc[i][j] = __builtin_amdgcn_mfma_scale_f32_16x16x128_f8f6f4(
                    bfr[j], af, acc[i][j], 0, 0,
                    0, 0x79797979,    // scale src0 (W): 2^-6
                    0, 0x7f7f7f7f);   // scale src1 (A): 2^0
        }
        __syncthreads();
    }

    // lane element (i,j,r): m = bm*256+wm*64+i*16+r16, n = bn*128+j*16+q*4+r
    if constexpr (MODE == 0) {
        // pack fp8 into padded LDS tile [256][132B] (aliases sA/sW -- safe
        // after the loop's trailing barrier), then coalesced dwordx4 stores.
        u8* eb = smem;
        int ml = wm * 64 + r16;
#pragma unroll
        for (int i = 0; i < 4; i++) {
#pragma unroll
            for (int j = 0; j < 8; j++) {
                int nl = j * 16 + q * 4;
                f32x4 b4 = *(const f32x4*)(bb + bn * 128 + nl);
                float v0 = fmaxf(acc[i][j][0] + b4[0], 0.0f);
                float v1 = fmaxf(acc[i][j][1] + b4[1], 0.0f);
                float v2 = fmaxf(acc[i][j][2] + b4[2], 0.0f);
                float v3 = fmaxf(acc[i][j][3] + b4[3], 0.0f);
                int p = __builtin_amdgcn_cvt_pk_fp8_f32(v0, v1, 0, false);
                p     = __builtin_amdgcn_cvt_pk_fp8_f32(v2, v3, p, true);
                *(int*)(eb + (ml + i * 16) * 132 + nl) = p;
            }
        }
        __syncthreads();
#pragma unroll
        for (int rd = 0; rd < 8; rd++) {
            int g2  = rd * 256 + t;
            int row = g2 >> 3, cc = g2 & 7;
            i32x4 v = *(const i32x4*)(eb + row * 132 + cc * 16);
            *(i32x4*)(O + (size_t)(bm * 256 + row) * NH + bn * 128 + cc * 16) = v;
        }
    } else {
#pragma unroll
        for (int i = 0; i < 4; i++) {
            float p0 = 0.f, p1 = 0.f, p2 = 0.f;
#pragma unroll
            for (int j = 0; j < 8; j++) {
                int nb = bn * 128 + j * 16 + q * 4;
                f32x4 b4 = *(const f32x4*)(bb + nb);
#pragma unroll
                for (int r = 0; r < 4; r++) {
                    float val = fmaxf(acc[i][j][r] + b4[r], 0.0f);
                    const float* w = Wout + (size_t)(nb + r) * NV;
                    p0 += val * w[0]; p1 += val * w[1]; p2 += val * w[2];
                }
            }
            // reduce over the 4 q-lanes (lane bits 4,5) holding the same m
            p0 += __shfl_xor(p0, 16); p0 += __shfl_xor(p0, 32);
            p1 += __shfl_xor(p1, 16); p1 += __shfl_xor(p1, 32);
            p2 += __shfl_xor(p2, 16); p2 += __shfl_xor(p2, 32);
            if (q == 0) {
                int m = bm * 256 + wm * 64 + i * 16 + r16;
                atomicAdd(&out[(size_t)m * NV + 0], p0);
                atomicAdd(&out[(size_t)m * NV + 1], p1);
                atomicAdd(&out[(size_t)m * NV + 2], p2);
            }
        }
    }
}

// ---------------------------------------------------------------------------
extern "C" void kernel_launch(void* const* d_in, const int* in_sizes, int n_in,
                              void* d_out, int out_size, void* d_ws, size_t ws_size,
                              hipStream_t stream) {
    const float* coords     = (const float*)d_in[0];
    const int*   latent_idx = (const int*)d_in[1];
    const float* latents    = (const float*)d_in[2];
    const float* codebooks  = (const float*)d_in[3];
    const float* mod_W      = (const float*)d_in[4];
    const float* mod_b      = (const float*)d_in[5];
    const float* dec_W0     = (const float*)d_in[6];
    const float* dec_b0     = (const float*)d_in[7];
    const float* dec_Wh     = (const float*)d_in[8];
    const float* dec_bh     = (const float*)d_in[9];
    const float* dec_Wout   = (const float*)d_in[10];
    const float* dec_bout   = (const float*)d_in[11];
    float* out = (float*)d_out;

    // ---- workspace layout (fixed part ~4.35 MB) ----
    char* wsb = (char*)d_ws;
    float* zq  = (float*)(wsb + 0);                        //      256 B
    float* bb  = (float*)(wsb + 256);                      //   20,480 B
    u8*    W0T = (u8*)(wsb + 20736);                       //  131,072 B  [1024][128]
    u8*    WhT = (u8*)(wsb + 151808);                      // 4,194,304 B [4][1024][1024]
    const size_t fixed_end = 4346368;                      // 256-aligned

    // adaptive chunk: cap 65536 (single chunk, ws ~139 MB), halve until fits;
    // floor 2048 so Mb = Bc/256 stays a multiple of 8 (capture-safe).
    int Bc = 65536;
    while (Bc > 2048 && fixed_end + 2 * (size_t)Bc * NH > ws_size)
        Bc >>= 1;
    int Mb = Bc / 256;   // m-tiles of 256

    u8* hA = (u8*)(wsb + fixed_end);                       // [Bc][1024] fp8
    u8* hB = hA + (size_t)Bc * NH;                         // [Bc][1024] fp8
    u8* pe = hB;   // pe [Bc][128] fp8 aliases hB (dead before layer-1 writes hB)

    // ---- one-time (per call) small kernels ----
    vq_kernel<<<1, 1024, 0, stream>>>(latents, latent_idx, codebooks, zq, out);
    betas_kernel<<<20, 256, 0, stream>>>(zq, mod_W, mod_b, dec_b0, dec_bh, bb);
    init_out_kernel<<<(NB * NV) / 256, 256, 0, stream>>>(dec_bout, out);
    prep_kernel<<<dim3(4, 32, 1), dim3(32, 8), 0, stream>>>(dec_W0, W0T, NIN, K0P);
    prep_kernel<<<dim3(32, 32, 4), dim3(32, 8), 0, stream>>>(dec_Wh, WhT, NH, NH);

    // ---- chunked 5-layer MLP, output layer fused into the last GEMM ----
    for (int c0 = 0; c0 < NB; c0 += Bc) {
        pe_kernel<<<(Bc * 32) / 256, 256, 0, stream>>>(coords + (size_t)c0 * NC, pe);
        gemm_kernel<0, K0P><<<8 * Mb, 256, 0, stream>>>(
            pe, W0T, bb + 0 * NH, hA, nullptr, nullptr, Mb);
        gemm_kernel<0, NH><<<8 * Mb, 256, 0, stream>>>(
            hA, WhT + 0 * (size_t)NH * NH, bb + 1 * NH, hB, nullptr, nullptr, Mb);
        gemm_kernel<0, NH><<<8 * Mb, 256, 0, stream>>>(
            hB, WhT + 1 * (size_t)NH * NH, bb + 2 * NH, hA, nullptr, nullptr, Mb);
        gemm_kernel<0, NH><<<8 * Mb, 256, 0, stream>>>(
            hA, WhT + 2 * (size_t)NH * NH, bb + 3 * NH, hB, nullptr, nullptr, Mb);
        gemm_kernel<1, NH><<<8 * Mb, 256, 0, stream>>>(
            hB, WhT + 3 * (size_t)NH * NH, bb + 4 * NH, nullptr,
            dec_Wout, out + (size_t)c0 * NV, Mb);
    }
}

// Round 11
// 511.667 us; speedup vs baseline: 4.2588x; 1.0091x over previous
//
#include <hip/hip_runtime.h>
#include <hip/hip_bf16.h>
#include <stdint.h>

// ---- problem constants ----
#define NB   65536      // batch points
#define NC   2
#define NV   3
#define ND   64
#define NK   1024       // codebook entries
#define NS   4
#define NH   1024
#define NL   5
#define NF   25
#define NIN  102
#define K0P  128        // padded layer-0 K

typedef float f32x4 __attribute__((ext_vector_type(4)));
typedef int   i32x4 __attribute__((ext_vector_type(4)));
typedef int   i32x8 __attribute__((ext_vector_type(8)));
typedef unsigned char u8;

// fp8 e4m3 scalar convert (RNE, saturating): low byte of cvt_pk
__device__ __forceinline__ u8 to_fp8(float x) {
    return (u8)(__builtin_amdgcn_cvt_pk_fp8_f32(x, 0.0f, 0, false) & 0xff);
}

// ===========================================================================
// TILED OPERAND LAYOUTS (R11) — fragment-order storage, zero-LDS K-loop.
//  W_t: flat = (((bn*nIt + it)*8 + j)*64 + lane)*32 + b   (lane = q*16+r16)
//       holds W[n][k], n = bn*128 + j*16 + r16, k = it*128 + q*32 + b.
//  A_t: flat = ((m16*(K/32) + c32)*16 + r)*32 + b
//       holds A[m][k], m = m16*16 + r, k = c32*32 + b.
//  A wave's fragment load = global_load_dwordx4 at base + lane*32 (+16):
//  one contiguous 1KB burst per instruction. No LDS, no barriers in K-loop.
// ===========================================================================

// ---------------------------------------------------------------------------
// VQ kernel: single block, 1024 threads (one codebook row per thread). fp32.
// ---------------------------------------------------------------------------
__global__ __launch_bounds__(1024) void vq_kernel(
    const float* __restrict__ latents, const int* __restrict__ latent_idx,
    const float* __restrict__ codebooks, float* __restrict__ zq_out,
    float* __restrict__ out) {
    __shared__ float zcur[ND], resid[ND], zqsum[ND], ssq[ND];
    __shared__ float sDw[16];
    __shared__ int   sKw[16];
    __shared__ int   sBest;
    int t = threadIdx.x, lane = t & 63, wv = t >> 6;
    const float* img = latents + (size_t)latent_idx[0] * (NS * ND);
    if (t < ND) { resid[t] = 0.f; zqsum[t] = 0.f; }
    __syncthreads();
    float lossAcc = 0.f;   // thread 0 only
    for (int s = 0; s < NS; s++) {
        if (t < ND) {
            float iv = img[s * ND + t];
            float r  = resid[t] + iv;
            resid[t] = r;
            zcur[t]  = (s == 0) ? iv : (r - zqsum[t]);
        }
        __syncthreads();
        float zz = 0.f;
#pragma unroll
        for (int d = 0; d < ND; d++) { float z = zcur[d]; zz += z * z; }
        const float4* e4 = (const float4*)(codebooks + ((size_t)s * NK + t) * ND);
        float dot = 0.f, ee = 0.f;
#pragma unroll
        for (int i = 0; i < 16; i++) {
            float4 v = e4[i];
            dot += zcur[4 * i + 0] * v.x; dot += zcur[4 * i + 1] * v.y;
            dot += zcur[4 * i + 2] * v.z; dot += zcur[4 * i + 3] * v.w;
            ee  += v.x * v.x; ee += v.y * v.y; ee += v.z * v.z; ee += v.w * v.w;
        }
        float dmin = zz - 2.0f * dot + ee;
        int   kmin = t;
#pragma unroll
        for (int m = 1; m < 64; m <<= 1) {
            float d2 = __shfl_xor(dmin, m);
            int   k2 = __shfl_xor(kmin, m);
            if (d2 < dmin || (d2 == dmin && k2 < kmin)) { dmin = d2; kmin = k2; }
        }
        if (lane == 0) { sDw[wv] = dmin; sKw[wv] = kmin; }
        __syncthreads();
        if (t == 0) {
            float bd = sDw[0]; int bk = sKw[0];
            for (int w = 1; w < 16; w++) {
                float d2 = sDw[w]; int k2 = sKw[w];
                if (d2 < bd || (d2 == bd && k2 < bk)) { bd = d2; bk = k2; }
            }
            sBest = bk;
            out[NB * NV + s] = (float)bk;
        }
        __syncthreads();
        int best = sBest;
        const float* eb = codebooks + ((size_t)s * NK + best) * ND;
        if (t < ND) {
            float zq = eb[t];
            float d  = zq - zcur[t];
            ssq[t]   = d * d;
            zqsum[t] = zqsum[t] + (zq + (zcur[t] - zq));   // z_q_st forward (exact ref arith)
        }
        __syncthreads();
        if (t == 0) {
            float sum = 0.f;
            for (int d = 0; d < ND; d++) sum += ssq[d];
            lossAcc += 0.25f * (sum / (float)ND);
        }
    }
    if (t < ND) zq_out[t] = zqsum[t];
    if (t == 0) out[NB * NV + NS] = lossAcc;
}

// ---------------------------------------------------------------------------
// betas fused with decoder biases (fp32)
// ---------------------------------------------------------------------------
__global__ __launch_bounds__(256) void betas_kernel(
    const float* __restrict__ zq, const float* __restrict__ mod_W,
    const float* __restrict__ mod_b, const float* __restrict__ b0,
    const float* __restrict__ bh, float* __restrict__ bb) {
    int g = blockIdx.x * 256 + threadIdx.x;   // < 5120
    int l = g >> 10, n = g & 1023;
    float acc = mod_b[g];
    for (int d = 0; d < ND; d++) acc += zq[d] * mod_W[(size_t)(l * ND + d) * NH + n];
    acc += (l == 0) ? b0[n] : bh[(size_t)(l - 1) * NH + n];
    bb[g] = acc;
}

// ---------------------------------------------------------------------------
// out init: values[m][v] = bout[v] (atomic-add target for the fused layer)
// ---------------------------------------------------------------------------
__global__ __launch_bounds__(256) void init_out_kernel(
    const float* __restrict__ bout, float* __restrict__ out) {
    int g = blockIdx.x * 256 + threadIdx.x;   // < NB*NV
    out[g] = bout[g % NV];
}

// ---------------------------------------------------------------------------
// Weight prep: fp32 [Ks][1024] -> fp8 e4m3 W_t tiled (x64, undone by the
// MFMA e8m0 scale 2^-6). Zero-pad k>=Ks. nIt = Kp/128.
// ---------------------------------------------------------------------------
__global__ __launch_bounds__(256) void prep_kernel(
    const float* __restrict__ src, u8* __restrict__ dst, int Ks, int Kp) {
    __shared__ float tile[32][33];
    int nIt = Kp >> 7;
    src += (size_t)blockIdx.z * Ks * NH;
    dst += (size_t)blockIdx.z * NH * Kp;
    int k0 = blockIdx.x * 32, n0 = blockIdx.y * 32;
    int tx = threadIdx.x, ty = threadIdx.y;   // (32, 8)
    for (int i = 0; i < 4; i++) {
        int k = k0 + ty + i * 8;
        int n = n0 + tx;
        tile[ty + i * 8][tx] = (k < Ks) ? src[(size_t)k * NH + n] : 0.0f;
    }
    __syncthreads();
    int it = k0 >> 7, q = (k0 >> 5) & 3;     // fixed per block (k0 % 32 == 0)
    for (int i = 0; i < 4; i++) {
        int n = n0 + ty + i * 8;
        int k = k0 + tx;
        int bn = n >> 7, j = (n >> 4) & 7, r16 = n & 15;
        size_t flat = ((size_t)(((bn * nIt + it) * 8 + j) * 64 + q * 16 + r16)) * 32 + tx;
        dst[flat] = to_fp8(tile[tx][ty + i * 8] * 64.0f);
    }
}

// ---------------------------------------------------------------------------
// Positional encoding -> fp8 A_t tiled [Bc][128] (K/32 = 4 chunks)
// ---------------------------------------------------------------------------
__device__ __forceinline__ float pe_val(const float* coords, int m, int k) {
    if (k < 2) return coords[m * 2 + k];
    if (k >= NIN) return 0.0f;
    int u = k - 2;
    int f = u >> 2, r = u & 3;
    float c = coords[m * 2 + (r & 1)];
    float a = c * __builtin_ldexpf(3.14159274101257324f, f);
    return (r < 2) ? sinf(a) : cosf(a);
}

__global__ __launch_bounds__(256) void pe_kernel(
    const float* __restrict__ coords, u8* __restrict__ pe) {
    int g = blockIdx.x * 256 + threadIdx.x;   // < Bc*32
    int m = g >> 5, k4 = (g & 31) * 4;
    float v0 = pe_val(coords, m, k4 + 0);
    float v1 = pe_val(coords, m, k4 + 1);
    float v2 = pe_val(coords, m, k4 + 2);
    float v3 = pe_val(coords, m, k4 + 3);
    int p = __builtin_amdgcn_cvt_pk_fp8_f32(v0, v1, 0, false);
    p     = __builtin_amdgcn_cvt_pk_fp8_f32(v2, v3, p, true);
    // A_t (K=128): flat = ((m16*4 + c32)*16 + r)*32 + b
    int m16 = m >> 4, r = m & 15, c32 = k4 >> 5, b = k4 & 31;
    *(int*)(pe + ((size_t)(m16 * 4 + c32) * 16 + r) * 32 + b) = p;
}

// ---------------------------------------------------------------------------
// MX-fp8 MFMA GEMM, R11: ZERO-LDS, ZERO-BARRIER K-loop on tiled operands.
// 256m x 128n block tile, 4 waves stacked in m, wave tile 64x128
// (acc[4][8] = 128 VGPRs). Every fragment = 2x global_load_dwordx4 at
// base + lane*32 (+16): contiguous 1KB bursts, L2-resident W. No
// __syncthreads in the loop -> loads pipeline freely under MFMA (the
// hipBLASLt-style structure; R10's barriered loop sat at 3700 cyc/block-iter
// vs ~1100 busy). Epilogue MODE 0 repacks into next layer's A_t via a 32KB
// LDS tile (2-way write alias = free) + coalesced 512B-burst stores.
// MODE 1: out[m][v] += relu(acc+bb).Wout[n][v], q-lane shfl + atomicAdd.
// ---------------------------------------------------------------------------
template <int MODE, int KT>
__global__ __launch_bounds__(256, 2) void gemm_kernel(
    const u8* __restrict__ A, const u8* __restrict__ W,
    const float* __restrict__ bb, u8* __restrict__ O,
    const float* __restrict__ Wout, float* __restrict__ out, int Mb) {
    __shared__ __align__(16) u8 smem[32768];   // epilogue repack only
    int t   = threadIdx.x;
    int fid = blockIdx.x;
    int xcd = fid & 7;
    int j8  = fid >> 3;                 // 0..Mb-1
    int bn  = j8 & 7;                   // fastest within an XCD
    int bm  = xcd * (Mb >> 3) + (j8 >> 3);
    int lane = t & 63, wm = t >> 6;     // wave owns m-slice wm*64..+63
    int q    = lane >> 4, r16 = lane & 15;
    const int nIt = KT >> 7;

    // W_t base for this bn (fragment j at +j*2048, iter at +8*2048)
    const u8* wbase = W + (size_t)(bn * nIt) * 16384 + lane * 32;
    // A_t bases: m16 = bm*16 + wm*4 + i, chunk stride (KT/32) per m16
    const u8* abase = A + ((size_t)(bm * 16 + wm * 4) * (KT >> 5)) * 512 + lane * 32;

    f32x4 acc[4][8];
    f32x4 zero = {0.f, 0.f, 0.f, 0.f};
    for (int i = 0; i < 4; i++)
        for (int j = 0; j < 8; j++) acc[i][j] = zero;

#pragma unroll 2
    for (int it = 0; it < nIt; it++) {
        i32x8 bfr[8];
#pragma unroll
        for (int j = 0; j < 8; j++) {
            const u8* p = wbase + (size_t)(it * 8 + j) * 2048;
            i32x4 lo = *(const i32x4*)(p);
            i32x4 hi = *(const i32x4*)(p + 16);
            bfr[j] = __builtin_shufflevector(lo, hi, 0, 1, 2, 3, 4, 5, 6, 7);
        }
#pragma unroll
        for (int i = 0; i < 4; i++) {
            const u8* p = abase + ((size_t)i * (KT >> 5) + it * 4) * 512;
            i32x4 lo = *(const i32x4*)(p);
            i32x4 hi = *(const i32x4*)(p + 16);
            i32x8 af = __builtin_shufflevector(lo, hi, 0, 1, 2, 3, 4, 5, 6, 7);
            // swapped operands: D rows (q*4+r) = n-dim(j), cols (r16) = m-dim(i)
#pragma unroll
            for (int j = 0; j < 8; j++)
                acc[i][j] = __builtin_amdgcn_mfma_scale_f32_16x16x128_f8f6f4(
                    bfr[j], af, acc[i][j], 0, 0,
                    0, 0x79797979,    // scale src0 (W): 2^-6
                    0, 0x7f7f7f7f);   // scale src1 (A): 2^0
        }
    }

    // lane element (i,j,r): m = bm*256+wm*64+i*16+r16, n = bn*128+j*16+q*4+r
    if constexpr (MODE == 0) {
        // Repack to next layer's A_t (K=1024, 32 chunks/m16). Local LDS tile:
        // [m16_l(16)][c32_l(4)][r(16)][32B]; this lane's int goes to
        // (m16_l = wm*4+i, c32_l = j>>1, r = r16, b = (j&1)*16 + q*4).
        u8* eb = smem;
#pragma unroll
        for (int i = 0; i < 4; i++) {
#pragma unroll
            for (int j = 0; j < 8; j++) {
                int nl = j * 16 + q * 4;
                f32x4 b4 = *(const f32x4*)(bb + bn * 128 + nl);
                float v0 = fmaxf(acc[i][j][0] + b4[0], 0.0f);
                float v1 = fmaxf(acc[i][j][1] + b4[1], 0.0f);
                float v2 = fmaxf(acc[i][j][2] + b4[2], 0.0f);
                float v3 = fmaxf(acc[i][j][3] + b4[3], 0.0f);
                int p = __builtin_amdgcn_cvt_pk_fp8_f32(v0, v1, 0, false);
                p     = __builtin_amdgcn_cvt_pk_fp8_f32(v2, v3, p, true);
                int idx = (((wm * 4 + i) * 4 + (j >> 1)) * 16 + r16) * 32
                        + (j & 1) * 16 + q * 4;
                *(int*)(eb + idx) = p;
            }
        }
        __syncthreads();
        // coalesced out: 64 segments of 512B; seg = (m16_l, c32_l) ->
        // global A_t offset ((bm*16+m16_l)*32 + bn*4 + c32_l)*512
#pragma unroll
        for (int rd = 0; rd < 8; rd++) {
            int g2  = rd * 256 + t;            // dwordx4 index 0..2047
            int seg = g2 >> 5, off = (g2 & 31) * 16;
            int m16l = seg >> 2, c32l = seg & 3;
            i32x4 v = *(const i32x4*)(eb + seg * 512 + off);
            *(i32x4*)(O + ((size_t)((bm * 16 + m16l) * 32 + bn * 4 + c32l)) * 512 + off) = v;
        }
    } else {
#pragma unroll
        for (int i = 0; i < 4; i++) {
            float p0 = 0.f, p1 = 0.f, p2 = 0.f;
#pragma unroll
            for (int j = 0; j < 8; j++) {
                int nb = bn * 128 + j * 16 + q * 4;
                f32x4 b4 = *(const f32x4*)(bb + nb);
#pragma unroll
                for (int r = 0; r < 4; r++) {
                    float val = fmaxf(acc[i][j][r] + b4[r], 0.0f);
                    const float* w = Wout + (size_t)(nb + r) * NV;
                    p0 += val * w[0]; p1 += val * w[1]; p2 += val * w[2];
                }
            }
            // reduce over the 4 q-lanes (lane bits 4,5) holding the same m
            p0 += __shfl_xor(p0, 16); p0 += __shfl_xor(p0, 32);
            p1 += __shfl_xor(p1, 16); p1 += __shfl_xor(p1, 32);
            p2 += __shfl_xor(p2, 16); p2 += __shfl_xor(p2, 32);
            if (q == 0) {
                int m = bm * 256 + wm * 64 + i * 16 + r16;
                atomicAdd(&out[(size_t)m * NV + 0], p0);
                atomicAdd(&out[(size_t)m * NV + 1], p1);
                atomicAdd(&out[(size_t)m * NV + 2], p2);
            }
        }
    }
}

// ---------------------------------------------------------------------------
extern "C" void kernel_launch(void* const* d_in, const int* in_sizes, int n_in,
                              void* d_out, int out_size, void* d_ws, size_t ws_size,
                              hipStream_t stream) {
    const float* coords     = (const float*)d_in[0];
    const int*   latent_idx = (const int*)d_in[1];
    const float* latents    = (const float*)d_in[2];
    const float* codebooks  = (const float*)d_in[3];
    const float* mod_W      = (const float*)d_in[4];
    const float* mod_b      = (const float*)d_in[5];
    const float* dec_W0     = (const float*)d_in[6];
    const float* dec_b0     = (const float*)d_in[7];
    const float* dec_Wh     = (const float*)d_in[8];
    const float* dec_bh     = (const float*)d_in[9];
    const float* dec_Wout   = (const float*)d_in[10];
    const float* dec_bout   = (const float*)d_in[11];
    float* out = (float*)d_out;

    // ---- workspace layout (fixed part ~4.35 MB) ----
    char* wsb = (char*)d_ws;
    float* zq  = (float*)(wsb + 0);                        //      256 B
    float* bb  = (float*)(wsb + 256);                      //   20,480 B
    u8*    W0T = (u8*)(wsb + 20736);                       //  131,072 B  tiled
    u8*    WhT = (u8*)(wsb + 151808);                      // 4,194,304 B tiled
    const size_t fixed_end = 4346368;                      // 256-aligned

    // adaptive chunk: cap 65536 (single chunk, ws ~139 MB), halve until fits;
    // floor 2048 so Mb = Bc/256 stays a multiple of 8 (capture-safe).
    int Bc = 65536;
    while (Bc > 2048 && fixed_end + 2 * (size_t)Bc * NH > ws_size)
        Bc >>= 1;
    int Mb = Bc / 256;   // m-tiles of 256

    u8* hA = (u8*)(wsb + fixed_end);                       // [Bc][1024] fp8 A_t
    u8* hB = hA + (size_t)Bc * NH;                         // [Bc][1024] fp8 A_t
    u8* pe = hB;   // pe A_t [Bc][128] aliases hB (dead before layer-1 writes hB)

    // ---- one-time (per call) small kernels ----
    vq_kernel<<<1, 1024, 0, stream>>>(latents, latent_idx, codebooks, zq, out);
    betas_kernel<<<20, 256, 0, stream>>>(zq, mod_W, mod_b, dec_b0, dec_bh, bb);
    init_out_kernel<<<(NB * NV) / 256, 256, 0, stream>>>(dec_bout, out);
    prep_kernel<<<dim3(4, 32, 1), dim3(32, 8), 0, stream>>>(dec_W0, W0T, NIN, K0P);
    prep_kernel<<<dim3(32, 32, 4), dim3(32, 8), 0, stream>>>(dec_Wh, WhT, NH, NH);

    // ---- chunked 5-layer MLP, output layer fused into the last GEMM ----
    for (int c0 = 0; c0 < NB; c0 += Bc) {
        pe_kernel<<<(Bc * 32) / 256, 256, 0, stream>>>(coords + (size_t)c0 * NC, pe);
        gemm_kernel<0, K0P><<<8 * Mb, 256, 0, stream>>>(
            pe, W0T, bb + 0 * NH, hA, nullptr, nullptr, Mb);
        gemm_kernel<0, NH><<<8 * Mb, 256, 0, stream>>>(
            hA, WhT + 0 * (size_t)NH * NH, bb + 1 * NH, hB, nullptr, nullptr, Mb);
        gemm_kernel<0, NH><<<8 * Mb, 256, 0, stream>>>(
            hB, WhT + 1 * (size_t)NH * NH, bb + 2 * NH, hA, nullptr, nullptr, Mb);
        gemm_kernel<0, NH><<<8 * Mb, 256, 0, stream>>>(
            hA, WhT + 2 * (size_t)NH * NH, bb + 3 * NH, hB, nullptr, nullptr, Mb);
        gemm_kernel<1, NH><<<8 * Mb, 256, 0, stream>>>(
            hB, WhT + 3 * (size_t)NH * NH, bb + 4 * NH, nullptr,
            dec_Wout, out + (size_t)c0 * NV, Mb);
    }
}

// Round 12
// 473.679 us; speedup vs baseline: 4.6004x; 1.0802x over previous
//
#include <hip/hip_runtime.h>
#include <hip/hip_bf16.h>
#include <stdint.h>

// ---- problem constants ----
#define NB   65536      // batch points
#define NC   2
#define NV   3
#define ND   64
#define NK   1024       // codebook entries
#define NS   4
#define NH   1024
#define NL   5
#define NF   25
#define NIN  102
#define K0P  128        // padded layer-0 K

typedef float f32x4 __attribute__((ext_vector_type(4)));
typedef int   i32x4 __attribute__((ext_vector_type(4)));
typedef int   i32x8 __attribute__((ext_vector_type(8)));
typedef unsigned char u8;

__device__ __forceinline__ void load_lds16(const void* g, void* l) {
    __builtin_amdgcn_global_load_lds(
        (const __attribute__((address_space(1))) void*)g,
        (__attribute__((address_space(3))) void*)l,
        16, 0, 0);
}

// fp8 e4m3 scalar convert (RNE, saturating): low byte of cvt_pk
__device__ __forceinline__ u8 to_fp8(float x) {
    return (u8)(__builtin_amdgcn_cvt_pk_fp8_f32(x, 0.0f, 0, false) & 0xff);
}

// ===========================================================================
// TILED OPERAND LAYOUTS (R12)
//  W_t: flat = (((bn*nIt + it)*8 + j)*2 + half)*1024 + (q*16+r16)*16 + b16
//       holds W[n][k]: n = bn*128 + j*16 + r16, k = it*128 + q*32 + half*16 + b16.
//       Per-(bn,it) slab = 16 KB contiguous -> global_load_lds staging;
//       frag ds_read = 2x b128 at stride-16 (conflict-free).
//  A_t: flat = ((m16*(K/32) + c32)*16 + r)*32 + b
//       holds A[m][k]: m = m16*16 + r, k = c32*32 + b. Direct-global frags.
// ===========================================================================

// ---------------------------------------------------------------------------
// VQ kernel: single block, 1024 threads (one codebook row per thread). fp32.
// ---------------------------------------------------------------------------
__global__ __launch_bounds__(1024) void vq_kernel(
    const float* __restrict__ latents, const int* __restrict__ latent_idx,
    const float* __restrict__ codebooks, float* __restrict__ zq_out,
    float* __restrict__ out) {
    __shared__ float zcur[ND], resid[ND], zqsum[ND], ssq[ND];
    __shared__ float sDw[16];
    __shared__ int   sKw[16];
    __shared__ int   sBest;
    int t = threadIdx.x, lane = t & 63, wv = t >> 6;
    const float* img = latents + (size_t)latent_idx[0] * (NS * ND);
    if (t < ND) { resid[t] = 0.f; zqsum[t] = 0.f; }
    __syncthreads();
    float lossAcc = 0.f;   // thread 0 only
    for (int s = 0; s < NS; s++) {
        if (t < ND) {
            float iv = img[s * ND + t];
            float r  = resid[t] + iv;
            resid[t] = r;
            zcur[t]  = (s == 0) ? iv : (r - zqsum[t]);
        }
        __syncthreads();
        float zz = 0.f;
#pragma unroll
        for (int d = 0; d < ND; d++) { float z = zcur[d]; zz += z * z; }
        const float4* e4 = (const float4*)(codebooks + ((size_t)s * NK + t) * ND);
        float dot = 0.f, ee = 0.f;
#pragma unroll
        for (int i = 0; i < 16; i++) {
            float4 v = e4[i];
            dot += zcur[4 * i + 0] * v.x; dot += zcur[4 * i + 1] * v.y;
            dot += zcur[4 * i + 2] * v.z; dot += zcur[4 * i + 3] * v.w;
            ee  += v.x * v.x; ee += v.y * v.y; ee += v.z * v.z; ee += v.w * v.w;
        }
        float dmin = zz - 2.0f * dot + ee;
        int   kmin = t;
#pragma unroll
        for (int m = 1; m < 64; m <<= 1) {
            float d2 = __shfl_xor(dmin, m);
            int   k2 = __shfl_xor(kmin, m);
            if (d2 < dmin || (d2 == dmin && k2 < kmin)) { dmin = d2; kmin = k2; }
        }
        if (lane == 0) { sDw[wv] = dmin; sKw[wv] = kmin; }
        __syncthreads();
        if (t == 0) {
            float bd = sDw[0]; int bk = sKw[0];
            for (int w = 1; w < 16; w++) {
                float d2 = sDw[w]; int k2 = sKw[w];
                if (d2 < bd || (d2 == bd && k2 < bk)) { bd = d2; bk = k2; }
            }
            sBest = bk;
            out[NB * NV + s] = (float)bk;
        }
        __syncthreads();
        int best = sBest;
        const float* eb = codebooks + ((size_t)s * NK + best) * ND;
        if (t < ND) {
            float zq = eb[t];
            float d  = zq - zcur[t];
            ssq[t]   = d * d;
            zqsum[t] = zqsum[t] + (zq + (zcur[t] - zq));   // z_q_st forward (exact ref arith)
        }
        __syncthreads();
        if (t == 0) {
            float sum = 0.f;
            for (int d = 0; d < ND; d++) sum += ssq[d];
            lossAcc += 0.25f * (sum / (float)ND);
        }
    }
    if (t < ND) zq_out[t] = zqsum[t];
    if (t == 0) out[NB * NV + NS] = lossAcc;
}

// ---------------------------------------------------------------------------
// betas fused with decoder biases (fp32)
// ---------------------------------------------------------------------------
__global__ __launch_bounds__(256) void betas_kernel(
    const float* __restrict__ zq, const float* __restrict__ mod_W,
    const float* __restrict__ mod_b, const float* __restrict__ b0,
    const float* __restrict__ bh, float* __restrict__ bb) {
    int g = blockIdx.x * 256 + threadIdx.x;   // < 5120
    int l = g >> 10, n = g & 1023;
    float acc = mod_b[g];
    for (int d = 0; d < ND; d++) acc += zq[d] * mod_W[(size_t)(l * ND + d) * NH + n];
    acc += (l == 0) ? b0[n] : bh[(size_t)(l - 1) * NH + n];
    bb[g] = acc;
}

// ---------------------------------------------------------------------------
// out init: values[m][v] = bout[v] (atomic-add target for the fused layer)
// ---------------------------------------------------------------------------
__global__ __launch_bounds__(256) void init_out_kernel(
    const float* __restrict__ bout, float* __restrict__ out) {
    int g = blockIdx.x * 256 + threadIdx.x;   // < NB*NV
    out[g] = bout[g % NV];
}

// ---------------------------------------------------------------------------
// Weight prep: fp32 [Ks][1024] -> fp8 e4m3 W_t tiled (x64, undone by the
// MFMA e8m0 scale 2^-6). Zero-pad k>=Ks. nIt = Kp/128. Half-split layout.
// ---------------------------------------------------------------------------
__global__ __launch_bounds__(256) void prep_kernel(
    const float* __restrict__ src, u8* __restrict__ dst, int Ks, int Kp) {
    __shared__ float tile[32][33];
    int nIt = Kp >> 7;
    src += (size_t)blockIdx.z * Ks * NH;
    dst += (size_t)blockIdx.z * NH * Kp;
    int k0 = blockIdx.x * 32, n0 = blockIdx.y * 32;
    int tx = threadIdx.x, ty = threadIdx.y;   // (32, 8)
    for (int i = 0; i < 4; i++) {
        int k = k0 + ty + i * 8;
        int n = n0 + tx;
        tile[ty + i * 8][tx] = (k < Ks) ? src[(size_t)k * NH + n] : 0.0f;
    }
    __syncthreads();
    for (int i = 0; i < 4; i++) {
        int n = n0 + ty + i * 8;
        int k = k0 + tx;
        int bn = n >> 7, j = (n >> 4) & 7, r16 = n & 15;
        int it = k >> 7, q = (k >> 5) & 3, half = (k >> 4) & 1, b16 = k & 15;
        size_t flat = ((size_t)(((bn * nIt + it) * 8 + j) * 2 + half)) * 1024
                    + (q * 16 + r16) * 16 + b16;
        dst[flat] = to_fp8(tile[tx][ty + i * 8] * 64.0f);
    }
}

// ---------------------------------------------------------------------------
// Positional encoding -> fp8 A_t tiled [Bc][128] (K/32 = 4 chunks)
// ---------------------------------------------------------------------------
__device__ __forceinline__ float pe_val(const float* coords, int m, int k) {
    if (k < 2) return coords[m * 2 + k];
    if (k >= NIN) return 0.0f;
    int u = k - 2;
    int f = u >> 2, r = u & 3;
    float c = coords[m * 2 + (r & 1)];
    float a = c * __builtin_ldexpf(3.14159274101257324f, f);
    return (r < 2) ? sinf(a) : cosf(a);
}

__global__ __launch_bounds__(256) void pe_kernel(
    const float* __restrict__ coords, u8* __restrict__ pe) {
    int g = blockIdx.x * 256 + threadIdx.x;   // < Bc*32
    int m = g >> 5, k4 = (g & 31) * 4;
    float v0 = pe_val(coords, m, k4 + 0);
    float v1 = pe_val(coords, m, k4 + 1);
    float v2 = pe_val(coords, m, k4 + 2);
    float v3 = pe_val(coords, m, k4 + 3);
    int p = __builtin_amdgcn_cvt_pk_fp8_f32(v0, v1, 0, false);
    p     = __builtin_amdgcn_cvt_pk_fp8_f32(v2, v3, p, true);
    // A_t (K=128): flat = ((m16*4 + c32)*16 + r)*32 + b
    int m16 = m >> 4, r = m & 15, c32 = k4 >> 5, b = k4 & 31;
    *(int*)(pe + ((size_t)(m16 * 4 + c32) * 16 + r) * 32 + b) = p;
}

// ---------------------------------------------------------------------------
// MX-fp8 MFMA GEMM, R12: explicit 1-iter software pipeline.
// 256m x 128n block tile, 4 waves stacked in m, wave tile 64x128
// (acc[4][8] = 128 AGPRs). W via LDS double-buffer (global_load_lds of the
// contiguous 16KB W_t slab; shared by all 4 waves; frag ds_read stride-16
// conflict-free). A via register prefetch (af_next, 32 VGPRs). ONE barrier
// per iter placed AFTER the ~1100-cyc MFMA block, so its vmcnt drain waits
// on loads issued a full compute-block earlier (R10/R11 both sat at 27%
// MfmaUtil because every load was issued right before its wait).
// MODE 0: relu(acc+bb) -> fp8, repack to next layer's A_t via LDS, coalesced.
// MODE 1: out[m][v] += relu(acc+bb).Wout[n][v], q-lane shfl + atomicAdd.
// ---------------------------------------------------------------------------
template <int MODE, int KT>
__global__ __launch_bounds__(256, 2) void gemm_kernel(
    const u8* __restrict__ A, const u8* __restrict__ W,
    const float* __restrict__ bb, u8* __restrict__ O,
    const float* __restrict__ Wout, float* __restrict__ out, int Mb) {
    __shared__ __align__(16) u8 smem[32768];
    u8* sW0 = smem;              // W buf 0 (16 KB)
    u8* sW1 = smem + 16384;      // W buf 1
    int t   = threadIdx.x;
    int fid = blockIdx.x;
    int xcd = fid & 7;
    int j8  = fid >> 3;                 // 0..Mb-1
    int bn  = j8 & 7;                   // fastest within an XCD
    int bm  = xcd * (Mb >> 3) + (j8 >> 3);
    int lane = t & 63, wm = t >> 6;     // wave owns m-slice wm*64..+63
    int q    = lane >> 4, r16 = lane & 15;
    const int nIt = KT >> 7;

    const u8* wslab = W + (size_t)(bn * nIt) * 16384;
    const u8* abase = A + ((size_t)(bm * 16 + wm * 4) * (KT >> 5)) * 512 + lane * 32;

    f32x4 acc[4][8];
    f32x4 zero = {0.f, 0.f, 0.f, 0.f};
    for (int i = 0; i < 4; i++)
        for (int j = 0; j < 8; j++) acc[i][j] = zero;

    // ---- prologue: stage W(it=0) into buf0, load A(it=0) into afc ----
#pragma unroll
    for (int p = 0; p < 4; p++) {
        int g = p * 256 + t;
        load_lds16((const void*)(wslab + g * 16), (void*)(sW0 + g * 16));
    }
    i32x8 afc[4], afn[4];
#pragma unroll
    for (int i = 0; i < 4; i++) {
        const u8* p = abase + ((size_t)i * (KT >> 5)) * 512;
        i32x4 lo = *(const i32x4*)(p);
        i32x4 hi = *(const i32x4*)(p + 16);
        afc[i] = __builtin_shufflevector(lo, hi, 0, 1, 2, 3, 4, 5, 6, 7);
    }
    __syncthreads();   // drains W staging + A loads

#pragma unroll 1
    for (int it = 0; it < nIt; it++) {
        u8* bufc = (it & 1) ? sW1 : sW0;
        u8* bufn = (it & 1) ? sW0 : sW1;
        // ---- issue next-iter loads FIRST (consumed after next barrier) ----
        if (it + 1 < nIt) {
            const u8* ws = wslab + (size_t)(it + 1) * 16384;
#pragma unroll
            for (int p = 0; p < 4; p++) {
                int g = p * 256 + t;
                load_lds16((const void*)(ws + g * 16), (void*)(bufn + g * 16));
            }
#pragma unroll
            for (int i = 0; i < 4; i++) {
                const u8* p = abase + ((size_t)i * (KT >> 5) + (it + 1) * 4) * 512;
                i32x4 lo = *(const i32x4*)(p);
                i32x4 hi = *(const i32x4*)(p + 16);
                afn[i] = __builtin_shufflevector(lo, hi, 0, 1, 2, 3, 4, 5, 6, 7);
            }
        }
        // ---- compute with current W buffer + afc (~1100 cyc of MFMA) ----
#pragma unroll
        for (int j = 0; j < 8; j++) {
            i32x4 lo = *(const i32x4*)(bufc + j * 2048 + lane * 16);
            i32x4 hi = *(const i32x4*)(bufc + j * 2048 + 1024 + lane * 16);
            i32x8 bfr = __builtin_shufflevector(lo, hi, 0, 1, 2, 3, 4, 5, 6, 7);
            // swapped operands: D rows (q*4+r) = n-dim(j), cols (r16) = m-dim(i)
#pragma unroll
            for (int i = 0; i < 4; i++)
                acc[i][j] = __builtin_amdgcn_mfma_scale_f32_16x16x128_f8f6f4(
                    bfr, afc[i], acc[i][j], 0, 0,
                    0, 0x79797979,    // scale src0 (W): 2^-6
                    0, 0x7f7f7f7f);   // scale src1 (A): 2^0
        }
        __syncthreads();   // drain: next W staged, next A landed, buf reads done
#pragma unroll
        for (int i = 0; i < 4; i++) afc[i] = afn[i];
    }

    // lane element (i,j,r): m = bm*256+wm*64+i*16+r16, n = bn*128+j*16+q*4+r
    if constexpr (MODE == 0) {
        // Repack to next layer's A_t (K=1024, 32 chunks/m16). Local LDS tile:
        // [m16_l(16)][c32_l(4)][r(16)][32B].
        u8* eb = smem;
#pragma unroll
        for (int i = 0; i < 4; i++) {
#pragma unroll
            for (int j = 0; j < 8; j++) {
                int nl = j * 16 + q * 4;
                f32x4 b4 = *(const f32x4*)(bb + bn * 128 + nl);
                float v0 = fmaxf(acc[i][j][0] + b4[0], 0.0f);
                float v1 = fmaxf(acc[i][j][1] + b4[1], 0.0f);
                float v2 = fmaxf(acc[i][j][2] + b4[2], 0.0f);
                float v3 = fmaxf(acc[i][j][3] + b4[3], 0.0f);
                int p = __builtin_amdgcn_cvt_pk_fp8_f32(v0, v1, 0, false);
                p     = __builtin_amdgcn_cvt_pk_fp8_f32(v2, v3, p, true);
                int idx = (((wm * 4 + i) * 4 + (j >> 1)) * 16 + r16) * 32
                        + (j & 1) * 16 + q * 4;
                *(int*)(eb + idx) = p;
            }
        }
        __syncthreads();
#pragma unroll
        for (int rd = 0; rd < 8; rd++) {
            int g2  = rd * 256 + t;            // dwordx4 index 0..2047
            int seg = g2 >> 5, off = (g2 & 31) * 16;
            int m16l = seg >> 2, c32l = seg & 3;
            i32x4 v = *(const i32x4*)(eb + seg * 512 + off);
            *(i32x4*)(O + ((size_t)((bm * 16 + m16l) * 32 + bn * 4 + c32l)) * 512 + off) = v;
        }
    } else {
#pragma unroll
        for (int i = 0; i < 4; i++) {
            float p0 = 0.f, p1 = 0.f, p2 = 0.f;
#pragma unroll
            for (int j = 0; j < 8; j++) {
                int nb = bn * 128 + j * 16 + q * 4;
                f32x4 b4 = *(const f32x4*)(bb + nb);
#pragma unroll
                for (int r = 0; r < 4; r++) {
                    float val = fmaxf(acc[i][j][r] + b4[r], 0.0f);
                    const float* w = Wout + (size_t)(nb + r) * NV;
                    p0 += val * w[0]; p1 += val * w[1]; p2 += val * w[2];
                }
            }
            // reduce over the 4 q-lanes (lane bits 4,5) holding the same m
            p0 += __shfl_xor(p0, 16); p0 += __shfl_xor(p0, 32);
            p1 += __shfl_xor(p1, 16); p1 += __shfl_xor(p1, 32);
            p2 += __shfl_xor(p2, 16); p2 += __shfl_xor(p2, 32);
            if (q == 0) {
                int m = bm * 256 + wm * 64 + i * 16 + r16;
                atomicAdd(&out[(size_t)m * NV + 0], p0);
                atomicAdd(&out[(size_t)m * NV + 1], p1);
                atomicAdd(&out[(size_t)m * NV + 2], p2);
            }
        }
    }
}

// ---------------------------------------------------------------------------
extern "C" void kernel_launch(void* const* d_in, const int* in_sizes, int n_in,
                              void* d_out, int out_size, void* d_ws, size_t ws_size,
                              hipStream_t stream) {
    const float* coords     = (const float*)d_in[0];
    const int*   latent_idx = (const int*)d_in[1];
    const float* latents    = (const float*)d_in[2];
    const float* codebooks  = (const float*)d_in[3];
    const float* mod_W      = (const float*)d_in[4];
    const float* mod_b      = (const float*)d_in[5];
    const float* dec_W0     = (const float*)d_in[6];
    const float* dec_b0     = (const float*)d_in[7];
    const float* dec_Wh     = (const float*)d_in[8];
    const float* dec_bh     = (const float*)d_in[9];
    const float* dec_Wout   = (const float*)d_in[10];
    const float* dec_bout   = (const float*)d_in[11];
    float* out = (float*)d_out;

    // ---- workspace layout (fixed part ~4.35 MB) ----
    char* wsb = (char*)d_ws;
    float* zq  = (float*)(wsb + 0);                        //      256 B
    float* bb  = (float*)(wsb + 256);                      //   20,480 B
    u8*    W0T = (u8*)(wsb + 20736);                       //  131,072 B  tiled
    u8*    WhT = (u8*)(wsb + 151808);                      // 4,194,304 B tiled
    const size_t fixed_end = 4346368;                      // 256-aligned

    // adaptive chunk: cap 65536 (single chunk, ws ~139 MB), halve until fits;
    // floor 2048 so Mb = Bc/256 stays a multiple of 8 (capture-safe).
    int Bc = 65536;
    while (Bc > 2048 && fixed_end + 2 * (size_t)Bc * NH > ws_size)
        Bc >>= 1;
    int Mb = Bc / 256;   // m-tiles of 256

    u8* hA = (u8*)(wsb + fixed_end);                       // [Bc][1024] fp8 A_t
    u8* hB = hA + (size_t)Bc * NH;                         // [Bc][1024] fp8 A_t
    u8* pe = hB;   // pe A_t [Bc][128] aliases hB (dead before layer-1 writes hB)

    // ---- one-time (per call) small kernels ----
    vq_kernel<<<1, 1024, 0, stream>>>(latents, latent_idx, codebooks, zq, out);
    betas_kernel<<<20, 256, 0, stream>>>(zq, mod_W, mod_b, dec_b0, dec_bh, bb);
    init_out_kernel<<<(NB * NV) / 256, 256, 0, stream>>>(dec_bout, out);
    prep_kernel<<<dim3(4, 32, 1), dim3(32, 8), 0, stream>>>(dec_W0, W0T, NIN, K0P);
    prep_kernel<<<dim3(32, 32, 4), dim3(32, 8), 0, stream>>>(dec_Wh, WhT, NH, NH);

    // ---- chunked 5-layer MLP, output layer fused into the last GEMM ----
    for (int c0 = 0; c0 < NB; c0 += Bc) {
        pe_kernel<<<(Bc * 32) / 256, 256, 0, stream>>>(coords + (size_t)c0 * NC, pe);
        gemm_kernel<0, K0P><<<8 * Mb, 256, 0, stream>>>(
            pe, W0T, bb + 0 * NH, hA, nullptr, nullptr, Mb);
        gemm_kernel<0, NH><<<8 * Mb, 256, 0, stream>>>(
            hA, WhT + 0 * (size_t)NH * NH, bb + 1 * NH, hB, nullptr, nullptr, Mb);
        gemm_kernel<0, NH><<<8 * Mb, 256, 0, stream>>>(
            hB, WhT + 1 * (size_t)NH * NH, bb + 2 * NH, hA, nullptr, nullptr, Mb);
        gemm_kernel<0, NH><<<8 * Mb, 256, 0, stream>>>(
            hA, WhT + 2 * (size_t)NH * NH, bb + 3 * NH, hB, nullptr, nullptr, Mb);
        gemm_kernel<1, NH><<<8 * Mb, 256, 0, stream>>>(
            hB, WhT + 3 * (size_t)NH * NH, bb + 4 * NH, nullptr,
            dec_Wout, out + (size_t)c0 * NV, Mb);
    }
}